// Round 5
// baseline (1113.565 us; speedup 1.0000x reference)
//
#include <hip/hip_runtime.h>
#include <math.h>

#define NN 16500
#define NP 16512      // 129 * 128 padded rows
#define NE 100000
#define KT 3

typedef __attribute__((ext_vector_type(8))) short bf8_t;   // 8 x bf16
typedef __attribute__((ext_vector_type(4))) float f4_t;    // MFMA accumulator

__device__ __forceinline__ unsigned short f2bf(float f) {
    unsigned int u = __float_as_uint(f);
    u += 0x7fffu + ((u >> 16) & 1u);   // RNE
    return (unsigned short)(u >> 16);
}
__device__ __forceinline__ float bf2f(unsigned short h) {
    return __uint_as_float(((unsigned int)h) << 16);
}

// ---------------- CSR build ----------------

__global__ void deg_kernel(const int* __restrict__ ei, int* __restrict__ deg) {
    int t = blockIdx.x * blockDim.x + threadIdx.x;
    if (t >= KT * NE) return;
    int k = t / NE, e = t - k * NE;
    int d = ei[k * 2 * NE + NE + e];
    atomicAdd(&deg[k * NN + d], 1);
}

__global__ void scan_kernel(const int* __restrict__ deg, int* __restrict__ offs,
                            int* __restrict__ cursor) {
    int k = blockIdx.x;
    const int* dg = deg + k * NN;
    int* of = offs + k * (NN + 1);
    int* cu = cursor + k * NN;
    __shared__ int part[256];
    int tid = threadIdx.x;
    const int chunk = (NN + 255) / 256;
    int s0 = tid * chunk, s1 = min(NN, s0 + chunk);
    if (s0 > s1) s0 = s1;
    int sum = 0;
    for (int i = s0; i < s1; ++i) sum += dg[i];
    part[tid] = sum;
    __syncthreads();
    for (int off = 1; off < 256; off <<= 1) {
        int v = part[tid];
        int vp = (tid >= off) ? part[tid - off] : 0;
        __syncthreads();
        part[tid] = v + vp;
        __syncthreads();
    }
    int run = (tid == 0) ? 0 : part[tid - 1];
    for (int i = s0; i < s1; ++i) {
        of[i] = run; cu[i] = run;
        run += dg[i];
    }
    if (tid == 255) of[NN] = run;
}

// scatter edge (src, ea) pairs directly in CSR order — removes one dependent
// gather level from the aggregation critical path.
__global__ void scatter_kernel(const int* __restrict__ ei, const float* __restrict__ ea,
                               int* __restrict__ cursor, int2* __restrict__ se) {
    int t = blockIdx.x * blockDim.x + threadIdx.x;
    if (t >= KT * NE) return;
    int k = t / NE, e = t - k * NE;
    int s = ei[k * 2 * NE + e];
    int d = ei[k * 2 * NE + NE + e];
    float a = ea[(size_t)k * NE + e];
    int pos = atomicAdd(&cursor[k * NN + d], 1);
    int2 p; p.x = s; p.y = __float_as_int(a);
    se[(size_t)k * NE + pos] = p;
}

// ---------------- softmax aggregation: one wave per (dst,k), 4 dsts/wave, depth-4 pipeline ----
// No-max online softmax: msg = relu(x_src + a*We + be) is bounded well below the
// fp32 exp overflow point for this BN-normalized pipeline, so we accumulate
// den = sum exp(msg), num = sum msg*exp(msg) directly.

template<int CI, bool BF16X>
__device__ __forceinline__ void loadrow4(float out[4], const void* xv, int s, int c0) {
    if (BF16X) {
        const unsigned short* xb = (const unsigned short*)xv;
        uint2 u = *(const uint2*)(xb + (size_t)s * CI + c0);
        out[0] = bf2f((unsigned short)(u.x & 0xffffu));
        out[1] = bf2f((unsigned short)(u.x >> 16));
        out[2] = bf2f((unsigned short)(u.y & 0xffffu));
        out[3] = bf2f((unsigned short)(u.y >> 16));
    } else {
        const float* p = (const float*)xv + (size_t)s * CI + c0;
        if (c0 + 4 <= CI) {
            float2 ab = *(const float2*)p;
            float2 cd = *(const float2*)(p + 2);
            out[0] = ab.x; out[1] = ab.y; out[2] = cd.x; out[3] = cd.y;
        } else {
            #pragma unroll
            for (int e = 0; e < 4; ++e) out[e] = (c0 + e < CI) ? p[e] : 0.f;
        }
    }
}

template<int CI, bool BF16X>
__global__ __launch_bounds__(256) void aggr_kernel(
    const void* __restrict__ xv, const int2* __restrict__ se_all,
    const int* __restrict__ offs_all,
    const float* __restrict__ We_all, const float* __restrict__ be_all,
    unsigned short* __restrict__ out_hi)
{
    constexpr int KP = (CI + 31) / 32 * 32;
    int k = blockIdx.y;
    int wv = threadIdx.x >> 6, lane = threadIdx.x & 63;
    int c0 = lane * 4;
    unsigned short* o = out_hi + (size_t)k * NP * KP;
    const int2*  se   = se_all + (size_t)k * NE;
    const int*   offs = offs_all + k * (NN + 1);
    const float* We   = We_all + (size_t)k * CI;
    const float* be   = be_all + (size_t)k * CI;

    constexpr bool ACT_ALL = (64 * 4 == KP) && (CI == KP);
    bool act = ACT_ALL || (c0 < CI);
    float w[4], b[4];
    #pragma unroll
    for (int e = 0; e < 4; ++e) {
        bool a = (c0 + e) < CI;
        w[e] = a ? We[c0 + e] : 0.f;
        b[e] = a ? be[c0 + e] : 0.f;
    }

    for (int it = 0; it < 4; ++it) {
        int d = blockIdx.x * 16 + it * 4 + wv;
        if (d >= NN) {
            if (c0 < KP) { uint2 z = {0u, 0u}; *(uint2*)(o + (size_t)d * KP + c0) = z; }
            continue;
        }
        float xd[4] = {0.f, 0.f, 0.f, 0.f};
        if (act) loadrow4<CI, BF16X>(xd, xv, d, c0);
        #pragma unroll
        for (int e = 0; e < 4; ++e) if ((c0 + e) >= CI) xd[e] = 0.f;

        float den[4], num[4];
        #pragma unroll
        for (int e = 0; e < 4; ++e) {
            float mg = fmaxf(xd[e] + w[e] + b[e], 0.f);   // self loop, ea=1
            float ex = __expf(mg);
            den[e] = ex;
            num[e] = mg * ex;
        }

        auto step = [&](const float xc[4], float a) {
            #pragma unroll
            for (int e = 0; e < 4; ++e) {
                float t = xc[e] + fmaf(a, w[e], b[e]);
                float mg = fmaxf(t, 0.f);
                float ex = __expf(mg);
                den[e] += ex;
                num[e] = fmaf(mg, ex, num[e]);
            }
        };

        int start = offs[d], end = offs[d + 1];
        for (int base = start; base < end; base += 64) {
            int cnt = min(64, end - base);
            int sv = 0; float av = 0.f;
            if (lane < cnt) {
                int2 p = se[base + lane];
                sv = p.x; av = __int_as_float(p.y);
            }
            float x0[4] = {0.f,0.f,0.f,0.f}, x1[4] = {0.f,0.f,0.f,0.f};
            float x2[4] = {0.f,0.f,0.f,0.f}, x3[4] = {0.f,0.f,0.f,0.f};
            {
                int sA = __shfl(sv, 0), sB = __shfl(sv, 1);
                int sC = __shfl(sv, 2), sD = __shfl(sv, 3);
                if (act)            loadrow4<CI, BF16X>(x0, xv, sA, c0);
                if (act && cnt > 1) loadrow4<CI, BF16X>(x1, xv, sB, c0);
                if (act && cnt > 2) loadrow4<CI, BF16X>(x2, xv, sC, c0);
                if (act && cnt > 3) loadrow4<CI, BF16X>(x3, xv, sD, c0);
            }
            int j = 0;
            for (; j + 3 < cnt; j += 4) {
                float a0 = __shfl(av, j),     a1 = __shfl(av, j + 1);
                float a2 = __shfl(av, j + 2), a3 = __shfl(av, j + 3);
                int s4 = __shfl(sv, (j + 4) & 63), s5 = __shfl(sv, (j + 5) & 63);
                int s6 = __shfl(sv, (j + 6) & 63), s7 = __shfl(sv, (j + 7) & 63);
                step(x0, a0);
                if (act && (j + 4) < cnt) loadrow4<CI, BF16X>(x0, xv, s4, c0);
                step(x1, a1);
                if (act && (j + 5) < cnt) loadrow4<CI, BF16X>(x1, xv, s5, c0);
                step(x2, a2);
                if (act && (j + 6) < cnt) loadrow4<CI, BF16X>(x2, xv, s6, c0);
                step(x3, a3);
                if (act && (j + 7) < cnt) loadrow4<CI, BF16X>(x3, xv, s7, c0);
            }
            if (j < cnt)     step(x0, __shfl(av, j));
            if (j + 1 < cnt) step(x1, __shfl(av, j + 1));
            if (j + 2 < cnt) step(x2, __shfl(av, j + 2));
        }
        if (c0 < KP) {
            unsigned short r[4];
            #pragma unroll
            for (int e = 0; e < 4; ++e) {
                float v = ((c0 + e) < CI) ? (num[e] / den[e] + xd[e]) : 0.f;
                r[e] = f2bf(v);
            }
            uint2 pk = {(unsigned)r[0] | ((unsigned)r[1] << 16),
                        (unsigned)r[2] | ((unsigned)r[3] << 16)};
            *(uint2*)(o + (size_t)d * KP + c0) = pk;
        }
    }
}

// ---------------- weight split+transpose, all 6 jobs in one launch ----------------

struct SplitJob { const float* W; unsigned short* out; int kdim, ndim, np_, kp; };
struct SplitJobs { SplitJob j[6]; };

__global__ void split_all_kernel(SplitJobs jobs) {
    SplitJob jb = jobs.j[blockIdx.z];
    int idx = blockIdx.x * 256 + threadIdx.x;
    int total = KT * jb.np_ * jb.kp;
    if (idx >= total) return;
    int k = idx / (jb.np_ * jb.kp);
    int rem = idx - k * jb.np_ * jb.kp;
    int n = rem / jb.kp;
    int kk = rem - n * jb.kp;
    float v = (n < jb.ndim && kk < jb.kdim) ? jb.W[((size_t)k * jb.kdim + kk) * jb.ndim + n] : 0.f;
    jb.out[idx] = f2bf(v);
}

// ---------------- GEMM1: direct-fragment bf16 MFMA, no LDS staging, no K-loop barriers -------
// Each lane loads its MFMA fragment straight from global memory: for 16x16x32, lane l
// holds A[row=l&15][k=(l>>4)*8 ..+8] = one contiguous 16B load. Wave w owns rows
// bm+16w..+15, all 128 block columns (A fragment bnpack/reuse factor 8). The compiler
// pipelines the per-k-step loads freely since there are no barriers in the loop.

__global__ __launch_bounds__(256, 3) void gemm1_mfma(
    const unsigned short* __restrict__ A_hi,
    const unsigned short* __restrict__ B_hi,
    const float* __restrict__ bias_all, unsigned short* __restrict__ C_all,
    float* __restrict__ psum,
    int KP, int ldc, int Nv)
{
    __shared__ float red[4][128][2];

    int z = blockIdx.z;
    int gxT = gridDim.x, gyT = gridDim.y;
    int NHP = gxT * 128;
    const unsigned short* A = A_hi + (size_t)z * NP * KP;
    const unsigned short* B = B_hi + (size_t)z * NHP * KP;
    const float* bias = bias_all + (size_t)z * Nv;
    unsigned short* C = C_all + (size_t)z * NP * ldc;

    int tid = threadIdx.x, w = tid >> 6, l = tid & 63;
    int bm = blockIdx.y * 64, bn = blockIdx.x * 128;
    int lane15 = l & 15, quad = l >> 4, kc8 = quad * 8;

    const unsigned short* ap = A + (size_t)(bm + w * 16 + lane15) * KP + kc8;
    const unsigned short* bp = B + (size_t)(bn + lane15) * KP + kc8;
    size_t bfs = (size_t)16 * KP;

    int NK = KP / 32;

    f4_t acc[8];
    #pragma unroll
    for (int cf = 0; cf < 8; ++cf) { f4_t zz = {0.f,0.f,0.f,0.f}; acc[cf] = zz; }

    bf8_t a_c = *(const bf8_t*)ap;
    bf8_t b_c[8];
    #pragma unroll
    for (int cf = 0; cf < 8; ++cf) b_c[cf] = *(const bf8_t*)(bp + cf * bfs);

    for (int ks = 0; ks < NK; ++ks) {
        bf8_t a_n, b_n[8];
        if (ks + 1 < NK) {
            int ko = (ks + 1) * 32;
            a_n = *(const bf8_t*)(ap + ko);
            #pragma unroll
            for (int cf = 0; cf < 8; ++cf) b_n[cf] = *(const bf8_t*)(bp + cf * bfs + ko);
        }
        #pragma unroll
        for (int cf = 0; cf < 8; ++cf)
            acc[cf] = __builtin_amdgcn_mfma_f32_16x16x32_bf16(a_c, b_c[cf], acc[cf], 0, 0, 0);
        a_c = a_n;
        #pragma unroll
        for (int cf = 0; cf < 8; ++cf) b_c[cf] = b_n[cf];
    }

    // epilogue: bf16 C write + fused BN partial stats (on quantized values)
    #pragma unroll
    for (int cf = 0; cf < 8; ++cf) {
        int c = bn + cf * 16 + lane15;
        float bc = (c < Nv) ? bias[c] : 0.f;
        float s1 = 0.f, s2 = 0.f;
        #pragma unroll
        for (int r5 = 0; r5 < 4; ++r5) {
            int r = bm + w * 16 + quad * 4 + r5;
            float v = acc[cf][r5] + bc;
            unsigned short q = f2bf(v);
            bool ok = (r < NN) && (c < Nv);
            if (ok) C[(size_t)r * ldc + c] = q;
            float vq = ok ? bf2f(q) : 0.f;
            s1 += vq;
            s2 = fmaf(vq, vq, s2);
        }
        s1 += __shfl_xor(s1, 16); s2 += __shfl_xor(s2, 16);
        s1 += __shfl_xor(s1, 32); s2 += __shfl_xor(s2, 32);
        if (quad == 0) {
            red[w][cf * 16 + lane15][0] = s1;
            red[w][cf * 16 + lane15][1] = s2;
        }
    }
    __syncthreads();
    if (tid < 128) {
        float S1 = red[0][tid][0] + red[1][tid][0] + red[2][tid][0] + red[3][tid][0];
        float S2 = red[0][tid][1] + red[1][tid][1] + red[2][tid][1] + red[3][tid][1];
        size_t o = (((size_t)z * gyT + blockIdx.y) * gxT + blockIdx.x) * 256 + tid * 2;
        psum[o] = S1;
        psum[o + 1] = S2;
    }
}

// ---------------- finalize BN scale/shift from per-block partials ----------------

__global__ __launch_bounds__(256) void finalize_kernel(
    const float* __restrict__ psum,
    const float* __restrict__ g_all, const float* __restrict__ bt_all,
    float* __restrict__ scale_all, float* __restrict__ shift_all,
    int hid, int gxT)
{
    int z = blockIdx.x;
    int t64 = threadIdx.x & 63;
    int slice = threadIdx.x >> 6;          // 0..3 row-block slices
    int c = blockIdx.y * 64 + t64;         // channel
    const int NBY = NP / 64;               // 258
    __shared__ double rs1[4][64];
    __shared__ double rs2[4][64];
    double s1 = 0.0, s2 = 0.0;
    if (c < gxT * 128) {
        int gx = c >> 7, col = c & 127;
        for (int by = slice; by < NBY; by += 4) {
            size_t base = (((size_t)z * NBY + by) * gxT + gx) * 256 + col * 2;
            s1 += (double)psum[base];
            s2 += (double)psum[base + 1];
        }
    }
    rs1[slice][t64] = s1;
    rs2[slice][t64] = s2;
    __syncthreads();
    if (slice == 0 && c < hid) {
        double S1 = rs1[0][t64] + rs1[1][t64] + rs1[2][t64] + rs1[3][t64];
        double S2 = rs2[0][t64] + rs2[1][t64] + rs2[2][t64] + rs2[3][t64];
        double mu = S1 / NN;
        double var = S2 / NN - mu * mu;
        if (var < 0.0) var = 0.0;
        float rs = (float)(1.0 / sqrt(var + 1e-5));
        float sc = rs * g_all[(size_t)z * hid + c];
        scale_all[(size_t)z * 512 + c] = sc;
        shift_all[(size_t)z * 512 + c] = bt_all[(size_t)z * hid + c] - (float)mu * sc;
    }
}

// ---------------- GEMM2: direct-fragment, z-fused accumulator, BN+ReLU on A in registers ----
// Zero barriers, zero LDS. Wave w owns rows bm+16w..+15; one bnpack per A-fragment
// serves all 8 column MFMAs. acc sums the 3 link types; fused bias+leaky epilogue.

__device__ __forceinline__ bf8_t bnpack8(bf8_t a, const float* __restrict__ scl,
                                         const float* __restrict__ shf,
                                         int nch, int hid) {
    float4 s0 = *(const float4*)(scl + nch);
    float4 s1 = *(const float4*)(scl + nch + 4);
    float4 t0 = *(const float4*)(shf + nch);
    float4 t1 = *(const float4*)(shf + nch + 4);
    float ss[8] = {s0.x, s0.y, s0.z, s0.w, s1.x, s1.y, s1.z, s1.w};
    float tt[8] = {t0.x, t0.y, t0.z, t0.w, t1.x, t1.y, t1.z, t1.w};
    bf8_t r;
    #pragma unroll
    for (int e = 0; e < 8; ++e) {
        float x = bf2f((unsigned short)a[e]);
        float val = (nch + e < hid) ? fmaxf(fmaf(x, ss[e], tt[e]), 0.f) : 0.f;
        r[e] = (short)f2bf(val);
    }
    return r;
}

__global__ __launch_bounds__(256, 3) void gemm2_mfma(
    const unsigned short* __restrict__ h_all, const float* __restrict__ scale_all,
    const float* __restrict__ shift_all,
    const unsigned short* __restrict__ B_hi,
    const float* __restrict__ bb,
    float* __restrict__ outf, unsigned short* __restrict__ outb,
    int KP, int hid, int leaky, int as_bf16)
{
    int tid = threadIdx.x, w = tid >> 6, l = tid & 63;
    int bm = blockIdx.y * 64, bn = blockIdx.x * 128;
    int lane15 = l & 15, quad = l >> 4, kc8 = quad * 8;

    const unsigned short* hp = h_all + (size_t)(bm + w * 16 + lane15) * KP + kc8;
    const unsigned short* bp = B_hi + (size_t)(bn + lane15) * KP + kc8;
    size_t bfs = (size_t)16 * KP;

    int NK = KP / 32, NIT = 3 * NK;

    f4_t acc[8];
    #pragma unroll
    for (int cf = 0; cf < 8; ++cf) { f4_t zz = {0.f,0.f,0.f,0.f}; acc[cf] = zz; }

    bf8_t a_c = *(const bf8_t*)hp;
    bf8_t b_c[8];
    #pragma unroll
    for (int cf = 0; cf < 8; ++cf) b_c[cf] = *(const bf8_t*)(bp + cf * bfs);

    int zc = 0, kk = 0;
    for (int it = 0; it < NIT; ++it) {
        int zn = zc, kn = kk + 32;
        if (kn == KP) { kn = 0; zn = zc + 1; }
        bf8_t a_n, b_n[8];
        if (it + 1 < NIT) {
            a_n = *(const bf8_t*)(hp + (size_t)zn * NP * KP + kn);
            const unsigned short* bz = bp + (size_t)zn * 256 * KP + kn;
            #pragma unroll
            for (int cf = 0; cf < 8; ++cf) b_n[cf] = *(const bf8_t*)(bz + cf * bfs);
        }
        int nch = kk + kc8;
        bf8_t fa = bnpack8(a_c, scale_all + zc * 512, shift_all + zc * 512, nch, hid);
        #pragma unroll
        for (int cf = 0; cf < 8; ++cf)
            acc[cf] = __builtin_amdgcn_mfma_f32_16x16x32_bf16(fa, b_c[cf], acc[cf], 0, 0, 0);
        a_c = a_n;
        #pragma unroll
        for (int cf = 0; cf < 8; ++cf) b_c[cf] = b_n[cf];
        zc = zn; kk = kn;
    }

    // epilogue: + sum-of-biases, leaky, store final (acc already sums the 3 link types)
    #pragma unroll
    for (int cf = 0; cf < 8; ++cf) {
        int c = bn + cf * 16 + lane15;
        float bsum = bb[c] + bb[256 + c] + bb[512 + c];
        #pragma unroll
        for (int r5 = 0; r5 < 4; ++r5) {
            int r = bm + w * 16 + quad * 4 + r5;
            if (r < NN) {
                float v = acc[cf][r5] + bsum;
                if (leaky) v = (v > 0.f) ? v : 0.01f * v;
                if (as_bf16) outb[(size_t)r * 256 + c] = f2bf(v);
                else         outf[(size_t)r * 256 + c] = v;
            }
        }
    }
}

// ---------------- host ----------------

extern "C" void kernel_launch(void* const* d_in, const int* in_sizes, int n_in,
                              void* d_out, int out_size, void* d_ws, size_t ws_size,
                              hipStream_t stream)
{
    const float* x  = (const float*)d_in[0];
    const int*   ei = (const int*)d_in[1];
    const float* ea = (const float*)d_in[2];

    char* w = (char*)d_ws;
    auto alloc = [&](size_t bytes) {
        char* p = w;
        w += (bytes + 255) & ~(size_t)255;
        return p;
    };
    int* deg    = (int*)alloc((size_t)KT * NN * 4);
    int* offs   = (int*)alloc((size_t)KT * (NN + 1) * 4);
    int* cursor = (int*)alloc((size_t)KT * NN * 4);
    int2* se    = (int2*)alloc((size_t)KT * NE * 8);
    unsigned short* a1_hi = (unsigned short*)alloc((size_t)KT * NP * 256 * 2);
    unsigned short* h3 = (unsigned short*)alloc((size_t)KT * NP * 512 * 2);
    unsigned short* bta_l[3];
    unsigned short* btb_l[3];
    for (int l = 0; l < 3; ++l) {
        bta_l[l] = (unsigned short*)alloc((size_t)KT * 512 * 256 * 2);
        btb_l[l] = (unsigned short*)alloc((size_t)KT * 256 * 512 * 2);
    }
    float* psum = (float*)alloc((size_t)KT * (NP / 64) * 4 * 256 * 4);
    float* scale3 = (float*)alloc((size_t)KT * 512 * 4);
    float* shift3 = (float*)alloc((size_t)KT * 512 * 4);
    unsigned short* bufA = (unsigned short*)alloc((size_t)NN * 256 * 2);
    unsigned short* bufB = (unsigned short*)alloc((size_t)NN * 256 * 2);

    hipMemsetAsync(deg, 0, (size_t)KT * NN * 4, stream);
    int net = KT * NE;
    deg_kernel<<<(net + 255) / 256, 256, 0, stream>>>(ei, deg);
    scan_kernel<<<KT, 256, 0, stream>>>(deg, offs, cursor);
    scatter_kernel<<<(net + 255) / 256, 256, 0, stream>>>(ei, ea, cursor, se);

    SplitJobs jobs;
    int maxtot = 0;
    for (int l = 0; l < 3; ++l) {
        int ci  = (l == 0) ? 170 : 256;
        int KP1 = (ci + 31) / 32 * 32;
        int hid = 2 * ci;
        int NHP = (hid + 127) / 128 * 128;
        int KP2 = (hid + 31) / 32 * 32;
        jobs.j[2 * l]     = { (const float*)d_in[3 + 8 * l + 2], bta_l[l], ci,  hid, NHP, KP1 };
        jobs.j[2 * l + 1] = { (const float*)d_in[3 + 8 * l + 6], btb_l[l], hid, 256, 256, KP2 };
        maxtot = max(maxtot, KT * NHP * KP1);
        maxtot = max(maxtot, KT * 256 * KP2);
    }
    dim3 gsp((maxtot + 255) / 256, 1, 6);
    split_all_kernel<<<gsp, 256, 0, stream>>>(jobs);

    const void* hin = x;
    for (int l = 0; l < 3; ++l) {
        int ci  = (l == 0) ? 170 : 256;
        int KP1 = (ci + 31) / 32 * 32;        // 192 / 256
        int hid = 2 * ci;                     // 340 / 512
        int NHP = (hid + 127) / 128 * 128;    // 384 / 512
        int KP2 = (hid + 31) / 32 * 32;       // 352 / 512
        const float* We = (const float*)d_in[3 + 8 * l + 0];
        const float* be = (const float*)d_in[3 + 8 * l + 1];
        const float* ba = (const float*)d_in[3 + 8 * l + 3];
        const float* g  = (const float*)d_in[3 + 8 * l + 4];
        const float* bt = (const float*)d_in[3 + 8 * l + 5];
        const float* bb = (const float*)d_in[3 + 8 * l + 7];

        dim3 ga(NP / 16, KT);
        if (l == 0)
            aggr_kernel<170, false><<<ga, 256, 0, stream>>>(hin, se, offs, We, be, a1_hi);
        else
            aggr_kernel<256, true><<<ga, 256, 0, stream>>>(hin, se, offs, We, be, a1_hi);

        dim3 g1(NHP / 128, NP / 64, KT);
        gemm1_mfma<<<g1, 256, 0, stream>>>(a1_hi, bta_l[l], ba, h3, psum, KP1, KP2, hid);

        dim3 gf(KT, 8);
        finalize_kernel<<<gf, 256, 0, stream>>>(psum, g, bt, scale3, shift3, hid, NHP / 128);

        unsigned short* outb = (l == 0) ? bufA : bufB;
        dim3 g2(2, NP / 64);
        gemm2_mfma<<<g2, 256, 0, stream>>>(h3, scale3, shift3, btb_l[l], bb,
                                           (float*)d_out, outb, KP2, hid,
                                           (l < 2) ? 1 : 0, (l < 2) ? 1 : 0);

        hin = (l < 2) ? (const void*)outb : nullptr;
    }
}

// Round 6
// 798.436 us; speedup vs baseline: 1.3947x; 1.3947x over previous
//
#include <hip/hip_runtime.h>
#include <math.h>

#define NN 16500
#define NP 16512      // 129 * 128 padded rows
#define NE 100000
#define KT 3

typedef __attribute__((ext_vector_type(8))) short bf8_t;   // 8 x bf16
typedef __attribute__((ext_vector_type(4))) float f4_t;    // MFMA accumulator

__device__ __forceinline__ unsigned short f2bf(float f) {
    unsigned int u = __float_as_uint(f);
    u += 0x7fffu + ((u >> 16) & 1u);   // RNE
    return (unsigned short)(u >> 16);
}
__device__ __forceinline__ float bf2f(unsigned short h) {
    return __uint_as_float(((unsigned int)h) << 16);
}
__device__ __forceinline__ void gload16(unsigned short* lds, const unsigned short* g) {
    __builtin_amdgcn_global_load_lds(
        (const __attribute__((address_space(1))) void*)g,
        (__attribute__((address_space(3))) void*)lds, 16, 0, 0);
}
// raw barrier; trailing fences pin subsequent LDS reads after it
__device__ __forceinline__ void pipe_barrier() {
    __builtin_amdgcn_s_barrier();
    __builtin_amdgcn_sched_barrier(0);
    asm volatile("" ::: "memory");
}

// ---------------- CSR build ----------------

__global__ void deg_kernel(const int* __restrict__ ei, int* __restrict__ deg) {
    int t = blockIdx.x * blockDim.x + threadIdx.x;
    if (t >= KT * NE) return;
    int k = t / NE, e = t - k * NE;
    int d = ei[k * 2 * NE + NE + e];
    atomicAdd(&deg[k * NN + d], 1);
}

__global__ void scan_kernel(const int* __restrict__ deg, int* __restrict__ offs,
                            int* __restrict__ cursor) {
    int k = blockIdx.x;
    const int* dg = deg + k * NN;
    int* of = offs + k * (NN + 1);
    int* cu = cursor + k * NN;
    __shared__ int part[256];
    int tid = threadIdx.x;
    const int chunk = (NN + 255) / 256;
    int s0 = tid * chunk, s1 = min(NN, s0 + chunk);
    if (s0 > s1) s0 = s1;
    int sum = 0;
    for (int i = s0; i < s1; ++i) sum += dg[i];
    part[tid] = sum;
    __syncthreads();
    for (int off = 1; off < 256; off <<= 1) {
        int v = part[tid];
        int vp = (tid >= off) ? part[tid - off] : 0;
        __syncthreads();
        part[tid] = v + vp;
        __syncthreads();
    }
    int run = (tid == 0) ? 0 : part[tid - 1];
    for (int i = s0; i < s1; ++i) {
        of[i] = run; cu[i] = run;
        run += dg[i];
    }
    if (tid == 255) of[NN] = run;
}

__global__ void scatter_kernel(const int* __restrict__ ei, const float* __restrict__ ea,
                               int* __restrict__ cursor, int2* __restrict__ se) {
    int t = blockIdx.x * blockDim.x + threadIdx.x;
    if (t >= KT * NE) return;
    int k = t / NE, e = t - k * NE;
    int s = ei[k * 2 * NE + e];
    int d = ei[k * 2 * NE + NE + e];
    float a = ea[(size_t)k * NE + e];
    int pos = atomicAdd(&cursor[k * NN + d], 1);
    int2 p; p.x = s; p.y = __float_as_int(a);
    se[(size_t)k * NE + pos] = p;
}

// ---------------- softmax aggregation (unchanged from round 3) ----------------

template<int CI, bool BF16X>
__device__ __forceinline__ void loadrow4(float out[4], const void* xv, int s, int c0) {
    if (BF16X) {
        const unsigned short* xb = (const unsigned short*)xv;
        uint2 u = *(const uint2*)(xb + (size_t)s * CI + c0);
        out[0] = bf2f((unsigned short)(u.x & 0xffffu));
        out[1] = bf2f((unsigned short)(u.x >> 16));
        out[2] = bf2f((unsigned short)(u.y & 0xffffu));
        out[3] = bf2f((unsigned short)(u.y >> 16));
    } else {
        const float* p = (const float*)xv + (size_t)s * CI + c0;
        if (c0 + 4 <= CI) {
            float2 ab = *(const float2*)p;
            float2 cd = *(const float2*)(p + 2);
            out[0] = ab.x; out[1] = ab.y; out[2] = cd.x; out[3] = cd.y;
        } else {
            #pragma unroll
            for (int e = 0; e < 4; ++e) out[e] = (c0 + e < CI) ? p[e] : 0.f;
        }
    }
}

template<int CI, bool BF16X>
__global__ __launch_bounds__(256) void aggr_kernel(
    const void* __restrict__ xv, const int2* __restrict__ se_all,
    const int* __restrict__ offs_all,
    const float* __restrict__ We_all, const float* __restrict__ be_all,
    unsigned short* __restrict__ out_hi)
{
    constexpr int KP = (CI + 31) / 32 * 32;
    int k = blockIdx.y;
    int wv = threadIdx.x >> 6, lane = threadIdx.x & 63;
    int c0 = lane * 4;
    unsigned short* o = out_hi + (size_t)k * NP * KP;
    const int2*  se   = se_all + (size_t)k * NE;
    const int*   offs = offs_all + k * (NN + 1);
    const float* We   = We_all + (size_t)k * CI;
    const float* be   = be_all + (size_t)k * CI;

    constexpr bool ACT_ALL = (64 * 4 == KP) && (CI == KP);
    bool act = ACT_ALL || (c0 < CI);
    float w[4], b[4];
    #pragma unroll
    for (int e = 0; e < 4; ++e) {
        bool a = (c0 + e) < CI;
        w[e] = a ? We[c0 + e] : 0.f;
        b[e] = a ? be[c0 + e] : 0.f;
    }

    for (int it = 0; it < 4; ++it) {
        int d = blockIdx.x * 16 + it * 4 + wv;
        if (d >= NN) {
            if (c0 < KP) { uint2 z = {0u, 0u}; *(uint2*)(o + (size_t)d * KP + c0) = z; }
            continue;
        }
        float xd[4] = {0.f, 0.f, 0.f, 0.f};
        if (act) loadrow4<CI, BF16X>(xd, xv, d, c0);
        #pragma unroll
        for (int e = 0; e < 4; ++e) if ((c0 + e) >= CI) xd[e] = 0.f;

        float den[4], num[4];
        #pragma unroll
        for (int e = 0; e < 4; ++e) {
            float mg = fmaxf(xd[e] + w[e] + b[e], 0.f);   // self loop, ea=1
            float ex = __expf(mg);
            den[e] = ex;
            num[e] = mg * ex;
        }

        auto step = [&](const float xc[4], float a) {
            #pragma unroll
            for (int e = 0; e < 4; ++e) {
                float t = xc[e] + fmaf(a, w[e], b[e]);
                float mg = fmaxf(t, 0.f);
                float ex = __expf(mg);
                den[e] += ex;
                num[e] = fmaf(mg, ex, num[e]);
            }
        };

        int start = offs[d], end = offs[d + 1];
        for (int base = start; base < end; base += 64) {
            int cnt = min(64, end - base);
            int sv = 0; float av = 0.f;
            if (lane < cnt) {
                int2 p = se[base + lane];
                sv = p.x; av = __int_as_float(p.y);
            }
            float x0[4] = {0.f,0.f,0.f,0.f}, x1[4] = {0.f,0.f,0.f,0.f};
            float x2[4] = {0.f,0.f,0.f,0.f}, x3[4] = {0.f,0.f,0.f,0.f};
            {
                int sA = __shfl(sv, 0), sB = __shfl(sv, 1);
                int sC = __shfl(sv, 2), sD = __shfl(sv, 3);
                if (act)            loadrow4<CI, BF16X>(x0, xv, sA, c0);
                if (act && cnt > 1) loadrow4<CI, BF16X>(x1, xv, sB, c0);
                if (act && cnt > 2) loadrow4<CI, BF16X>(x2, xv, sC, c0);
                if (act && cnt > 3) loadrow4<CI, BF16X>(x3, xv, sD, c0);
            }
            int j = 0;
            for (; j + 3 < cnt; j += 4) {
                float a0 = __shfl(av, j),     a1 = __shfl(av, j + 1);
                float a2 = __shfl(av, j + 2), a3 = __shfl(av, j + 3);
                int s4 = __shfl(sv, (j + 4) & 63), s5 = __shfl(sv, (j + 5) & 63);
                int s6 = __shfl(sv, (j + 6) & 63), s7 = __shfl(sv, (j + 7) & 63);
                step(x0, a0);
                if (act && (j + 4) < cnt) loadrow4<CI, BF16X>(x0, xv, s4, c0);
                step(x1, a1);
                if (act && (j + 5) < cnt) loadrow4<CI, BF16X>(x1, xv, s5, c0);
                step(x2, a2);
                if (act && (j + 6) < cnt) loadrow4<CI, BF16X>(x2, xv, s6, c0);
                step(x3, a3);
                if (act && (j + 7) < cnt) loadrow4<CI, BF16X>(x3, xv, s7, c0);
            }
            if (j < cnt)     step(x0, __shfl(av, j));
            if (j + 1 < cnt) step(x1, __shfl(av, j + 1));
            if (j + 2 < cnt) step(x2, __shfl(av, j + 2));
        }
        if (c0 < KP) {
            unsigned short r[4];
            #pragma unroll
            for (int e = 0; e < 4; ++e) {
                float v = ((c0 + e) < CI) ? (num[e] / den[e] + xd[e]) : 0.f;
                r[e] = f2bf(v);
            }
            uint2 pk = {(unsigned)r[0] | ((unsigned)r[1] << 16),
                        (unsigned)r[2] | ((unsigned)r[3] << 16)};
            *(uint2*)(o + (size_t)d * KP + c0) = pk;
        }
    }
}

// ---------------- weight split+transpose ----------------

struct SplitJob { const float* W; unsigned short* out; int kdim, ndim, np_, kp; };
struct SplitJobs { SplitJob j[6]; };

__global__ void split_all_kernel(SplitJobs jobs) {
    SplitJob jb = jobs.j[blockIdx.z];
    int idx = blockIdx.x * 256 + threadIdx.x;
    int total = KT * jb.np_ * jb.kp;
    if (idx >= total) return;
    int k = idx / (jb.np_ * jb.kp);
    int rem = idx - k * jb.np_ * jb.kp;
    int n = rem / jb.kp;
    int kk = rem - n * jb.kp;
    float v = (n < jb.ndim && kk < jb.kdim) ? jb.W[((size_t)k * jb.kdim + kk) * jb.ndim + n] : 0.f;
    jb.out[idx] = f2bf(v);
}

// ---------------- GEMM1: 128x128 tile, 4-slot LDS ring, depth-2 counted-vmcnt pipeline --------
// Slot safety: 1 barrier/iter bounds wave skew to 1 iteration; stage(i+2) targets slot
// (i+2)&3, whose last readers (tile i-2) retired their ds_reads before barrier(i-2) —
// and the stage is issued after barrier(i-1). vmcnt(8) leaves exactly the 8 DMA of
// stages i+1 and i+2 in flight (in-order retirement), so tile i has landed; the barrier
// then publishes every wave's DMA. Clamped tail staging keeps the in-flight count static.

template<int KP>
__global__ __launch_bounds__(256, 2) void gemm1_mfma(
    const unsigned short* __restrict__ A_hi,
    const unsigned short* __restrict__ B_hi,
    const float* __restrict__ bias_all, unsigned short* __restrict__ C_all,
    float* __restrict__ psum, int ldc, int Nv)
{
    constexpr int NK = KP / 32;
    constexpr int SLOT = 128 * 32;
    __shared__ unsigned short Ah[4 * SLOT];
    __shared__ unsigned short Bh[4 * SLOT];

    int z = blockIdx.z;
    int gxT = gridDim.x, gyT = gridDim.y;
    int NHP = gxT * 128;
    const unsigned short* Ahg = A_hi + (size_t)z * NP * KP;
    const unsigned short* Bhg = B_hi + (size_t)z * NHP * KP;
    const float* bias = bias_all + (size_t)z * Nv;
    unsigned short* C = C_all + (size_t)z * NP * ldc;

    int tid = threadIdx.x, w = tid >> 6, l = tid & 63;
    int bm = blockIdx.y * 128, bn = blockIdx.x * 128;
    int lane15 = l & 15, quad = l >> 4;
    int wm = (w >> 1) * 64, wn = (w & 1) * 64;
    int srow = l & 15, scol = quad * 8;

    size_t aoff0 = (size_t)(bm + 32 * w + srow) * KP + scol;
    size_t aoff1 = aoff0 + (size_t)16 * KP;
    size_t boff0 = (size_t)(bn + 32 * w + srow) * KP + scol;
    size_t boff1 = boff0 + (size_t)16 * KP;
    int rb0 = (2 * w) * 512, rb1 = (2 * w + 1) * 512;
    int ta = (w >> 1) * 4, tb = (w & 1) * 4;

    f4_t acc[4][4];
    #pragma unroll
    for (int i = 0; i < 4; ++i)
        #pragma unroll
        for (int j = 0; j < 4; ++j) { f4_t zz = {0.f,0.f,0.f,0.f}; acc[i][j] = zz; }

    auto stage = [&](int t, int s) {
        int k0 = t * 32;
        gload16(&Ah[s * SLOT + rb0], Ahg + aoff0 + k0);
        gload16(&Ah[s * SLOT + rb1], Ahg + aoff1 + k0);
        gload16(&Bh[s * SLOT + rb0], Bhg + boff0 + k0);
        gload16(&Bh[s * SLOT + rb1], Bhg + boff1 + k0);
    };
    stage(0, 0);
    stage(1, 1);

    #pragma unroll
    for (int i = 0; i < NK; ++i) {
        stage(min(i + 2, NK - 1), (i + 2) & 3);
        asm volatile("s_waitcnt vmcnt(8)" ::: "memory");
        pipe_barrier();
        const unsigned short* As = &Ah[(i & 3) * SLOT];
        const unsigned short* Bs = &Bh[(i & 3) * SLOT];
        bf8_t fa[4], fb[4];
        #pragma unroll
        for (int q = 0; q < 4; ++q) {
            fa[q] = *(const bf8_t*)&As[(ta + q) * 512 + l * 8];
            fb[q] = *(const bf8_t*)&Bs[(tb + q) * 512 + l * 8];
        }
        #pragma unroll
        for (int q = 0; q < 4; ++q)
            #pragma unroll
            for (int j = 0; j < 4; ++j)
                acc[q][j] = __builtin_amdgcn_mfma_f32_16x16x32_bf16(fa[q], fb[j], acc[q][j], 0, 0, 0);
    }

    // epilogue: bf16 C write + fused BN partial stats (on quantized values)
    #pragma unroll
    for (int j = 0; j < 4; ++j) {
        int c = bn + wn + j * 16 + lane15;
        float bc = (c < Nv) ? bias[c] : 0.f;
        float s1 = 0.f, s2 = 0.f;
        #pragma unroll
        for (int i = 0; i < 4; ++i) {
            #pragma unroll
            for (int r5 = 0; r5 < 4; ++r5) {
                int r = bm + wm + i * 16 + quad * 4 + r5;
                float v = acc[i][j][r5] + bc;
                unsigned short q = f2bf(v);
                bool ok = (r < NN) && (c < Nv);
                if (ok) C[(size_t)r * ldc + c] = q;
                float vq = ok ? bf2f(q) : 0.f;
                s1 += vq;
                s2 = fmaf(vq, vq, s2);
            }
        }
        s1 += __shfl_xor(s1, 16); s2 += __shfl_xor(s2, 16);
        s1 += __shfl_xor(s1, 32); s2 += __shfl_xor(s2, 32);
        if (quad == 0) {
            int wrow = w >> 1;
            int col = wn + j * 16 + lane15;
            size_t o = ((((size_t)z * gyT + blockIdx.y) * gxT + blockIdx.x) * 2 + wrow) * 256 + col * 2;
            float2 st = {s1, s2};
            *(float2*)&psum[o] = st;
        }
    }
}

// ---------------- finalize BN scale/shift from partials ----------------

__global__ __launch_bounds__(256) void finalize_kernel(
    const float* __restrict__ psum,
    const float* __restrict__ g_all, const float* __restrict__ bt_all,
    float* __restrict__ scale_all, float* __restrict__ shift_all,
    int hid, int gxT)
{
    int z = blockIdx.x;
    int t64 = threadIdx.x & 63;
    int slice = threadIdx.x >> 6;          // 0..3 gy-slices
    int c = blockIdx.y * 64 + t64;         // channel
    __shared__ double rs1[4][64];
    __shared__ double rs2[4][64];
    double s1 = 0.0, s2 = 0.0;
    if (c < gxT * 128) {
        int gx = c >> 7, col = c & 127;
        for (int gy = slice; gy < NP / 128; gy += 4) {
            size_t base = (((size_t)z * (NP / 128) + gy) * gxT + gx) * 2 * 256 + col * 2;
            float2 a  = *(const float2*)&psum[base];
            float2 b2 = *(const float2*)&psum[base + 256];
            s1 += (double)a.x + b2.x;
            s2 += (double)a.y + b2.y;
        }
    }
    rs1[slice][t64] = s1;
    rs2[slice][t64] = s2;
    __syncthreads();
    if (slice == 0 && c < hid) {
        double S1 = rs1[0][t64] + rs1[1][t64] + rs1[2][t64] + rs1[3][t64];
        double S2 = rs2[0][t64] + rs2[1][t64] + rs2[2][t64] + rs2[3][t64];
        double mu = S1 / NN;
        double var = S2 / NN - mu * mu;
        if (var < 0.0) var = 0.0;
        float rs = (float)(1.0 / sqrt(var + 1e-5));
        float sc = rs * g_all[(size_t)z * hid + c];
        scale_all[(size_t)z * 512 + c] = sc;
        shift_all[(size_t)z * 512 + c] = bt_all[(size_t)z * hid + c] - (float)mu * sc;
    }
}

// ---------------- GEMM2: z-fused, 64x128 tile, 4-slot ring, counted vmcnt ----------------
// A staged RAW via gload_lds (no reg roundtrip); BN+ReLU applied in registers after the
// fragment ds_read, with scale/shift served from an LDS copy so no VMEM op other than
// the 3 stage-DMAs exists in the loop (keeps vmcnt(6) accounting exact). KP is padded
// to a 64 multiple; channels >= hid are zeroed in the transform (B is zero there too).

template<int KP>
__global__ __launch_bounds__(256, 2) void gemm2_mfma(
    const unsigned short* __restrict__ h_all, const float* __restrict__ scale_all,
    const float* __restrict__ shift_all,
    const unsigned short* __restrict__ B_hi,
    const float* __restrict__ bb,
    float* __restrict__ outf, unsigned short* __restrict__ outb,
    int hid, int leaky, int as_bf16)
{
    constexpr int NK = KP / 32;
    constexpr int NIT = 3 * NK;
    constexpr int ASLOT = 64 * 32;    // 2048 shorts
    constexpr int BSLOT = 128 * 32;   // 4096 shorts
    __shared__ unsigned short Ah[4 * ASLOT];
    __shared__ unsigned short Bh[4 * BSLOT];
    __shared__ __align__(16) float sclS[KT * 512];
    __shared__ __align__(16) float shfS[KT * 512];

    int tid = threadIdx.x, w = tid >> 6, l = tid & 63;
    int bm = blockIdx.y * 64, bn = blockIdx.x * 128;
    int lane15 = l & 15, quad = l >> 4;
    int wm = (w >> 1) * 32, wn = (w & 1) * 64;
    int srow = l & 15, scol = quad * 8;
    int ta = (w >> 1) * 2, tb = (w & 1) * 4;

    size_t ao  = (size_t)(bm + 16 * w + srow) * KP + scol;   // wave w stages A fragrow w
    size_t bo0 = (size_t)(bn + 32 * w + srow) * KP + scol;
    size_t bo1 = bo0 + (size_t)16 * KP;
    int adst = w * 512;
    int bdst0 = (2 * w) * 512, bdst1 = (2 * w + 1) * 512;

    // prologue: copy scale/shift to LDS (removes in-loop VMEM), stage tiles 0,1
    for (int idx = tid; idx < KT * 512; idx += 256) {
        sclS[idx] = scale_all[idx];
        shfS[idx] = shift_all[idx];
    }
    auto stage = [&](int t, int s) {
        int zz = t / NK, kk = (t - zz * NK) * 32;
        const unsigned short* hz = h_all + (size_t)zz * NP * KP + kk;
        const unsigned short* bz = B_hi + (size_t)zz * 256 * KP + kk;
        gload16(&Ah[s * ASLOT + adst], hz + ao);
        gload16(&Bh[s * BSLOT + bdst0], bz + bo0);
        gload16(&Bh[s * BSLOT + bdst1], bz + bo1);
    };
    stage(0, 0);
    stage(1, 1);
    __syncthreads();   // one-time full drain: publishes sclS (and tiles 0,1)

    f4_t acc[2][4];
    #pragma unroll
    for (int i = 0; i < 2; ++i)
        #pragma unroll
        for (int j = 0; j < 4; ++j) { f4_t zz = {0.f,0.f,0.f,0.f}; acc[i][j] = zz; }

    #pragma unroll 4
    for (int i = 0; i < NIT; ++i) {
        stage(min(i + 2, NIT - 1), (i + 2) & 3);
        asm volatile("s_waitcnt vmcnt(6)" ::: "memory");
        pipe_barrier();
        int zz = i / NK, kk = (i - zz * NK) * 32;
        int chb = kk + quad * 8;
        const float* scl = &sclS[zz * 512 + chb];
        const float* shf = &shfS[zz * 512 + chb];
        float4 s0 = *(const float4*)scl, s1 = *(const float4*)(scl + 4);
        float4 t0 = *(const float4*)shf, t1 = *(const float4*)(shf + 4);
        float ss[8] = {s0.x, s0.y, s0.z, s0.w, s1.x, s1.y, s1.z, s1.w};
        float tt[8] = {t0.x, t0.y, t0.z, t0.w, t1.x, t1.y, t1.z, t1.w};
        const unsigned short* As = &Ah[(i & 3) * ASLOT];
        const unsigned short* Bs = &Bh[(i & 3) * BSLOT];
        bf8_t far0 = *(const bf8_t*)&As[(ta + 0) * 512 + l * 8];
        bf8_t far1 = *(const bf8_t*)&As[(ta + 1) * 512 + l * 8];
        bf8_t fb[4];
        #pragma unroll
        for (int j = 0; j < 4; ++j) fb[j] = *(const bf8_t*)&Bs[(tb + j) * 512 + l * 8];
        bf8_t fa0, fa1;
        #pragma unroll
        for (int e = 0; e < 8; ++e) {
            bool okc = (chb + e) < hid;
            float x0 = bf2f((unsigned short)far0[e]);
            float x1 = bf2f((unsigned short)far1[e]);
            float v0 = okc ? fmaxf(fmaf(x0, ss[e], tt[e]), 0.f) : 0.f;
            float v1 = okc ? fmaxf(fmaf(x1, ss[e], tt[e]), 0.f) : 0.f;
            fa0[e] = (short)f2bf(v0);
            fa1[e] = (short)f2bf(v1);
        }
        #pragma unroll
        for (int j = 0; j < 4; ++j) {
            acc[0][j] = __builtin_amdgcn_mfma_f32_16x16x32_bf16(fa0, fb[j], acc[0][j], 0, 0, 0);
            acc[1][j] = __builtin_amdgcn_mfma_f32_16x16x32_bf16(fa1, fb[j], acc[1][j], 0, 0, 0);
        }
    }

    // epilogue: + sum-of-biases, leaky, store final (acc already sums the 3 link types)
    #pragma unroll
    for (int j = 0; j < 4; ++j) {
        int c = bn + wn + j * 16 + lane15;
        float bsum = bb[c] + bb[256 + c] + bb[512 + c];
        #pragma unroll
        for (int i2 = 0; i2 < 2; ++i2) {
            #pragma unroll
            for (int r5 = 0; r5 < 4; ++r5) {
                int r = bm + wm + i2 * 16 + quad * 4 + r5;
                if (r < NN) {
                    float v = acc[i2][j][r5] + bsum;
                    if (leaky) v = (v > 0.f) ? v : 0.01f * v;
                    if (as_bf16) outb[(size_t)r * 256 + c] = f2bf(v);
                    else         outf[(size_t)r * 256 + c] = v;
                }
            }
        }
    }
}

// ---------------- host ----------------

extern "C" void kernel_launch(void* const* d_in, const int* in_sizes, int n_in,
                              void* d_out, int out_size, void* d_ws, size_t ws_size,
                              hipStream_t stream)
{
    const float* x  = (const float*)d_in[0];
    const int*   ei = (const int*)d_in[1];
    const float* ea = (const float*)d_in[2];

    char* w = (char*)d_ws;
    auto alloc = [&](size_t bytes) {
        char* p = w;
        w += (bytes + 255) & ~(size_t)255;
        return p;
    };
    int* deg    = (int*)alloc((size_t)KT * NN * 4);
    int* offs   = (int*)alloc((size_t)KT * (NN + 1) * 4);
    int* cursor = (int*)alloc((size_t)KT * NN * 4);
    int2* se    = (int2*)alloc((size_t)KT * NE * 8);
    unsigned short* a1_hi = (unsigned short*)alloc((size_t)KT * NP * 256 * 2);
    unsigned short* h3 = (unsigned short*)alloc((size_t)KT * NP * 512 * 2);
    unsigned short* bta_l[3];
    unsigned short* btb_l[3];
    for (int l = 0; l < 3; ++l) {
        bta_l[l] = (unsigned short*)alloc((size_t)KT * 512 * 256 * 2);
        btb_l[l] = (unsigned short*)alloc((size_t)KT * 256 * 512 * 2);
    }
    float* psum = (float*)alloc((size_t)KT * (NP / 128) * 4 * 2 * 256 * 4);
    float* scale3 = (float*)alloc((size_t)KT * 512 * 4);
    float* shift3 = (float*)alloc((size_t)KT * 512 * 4);
    unsigned short* bufA = (unsigned short*)alloc((size_t)NN * 256 * 2);
    unsigned short* bufB = (unsigned short*)alloc((size_t)NN * 256 * 2);

    hipMemsetAsync(deg, 0, (size_t)KT * NN * 4, stream);
    int net = KT * NE;
    deg_kernel<<<(net + 255) / 256, 256, 0, stream>>>(ei, deg);
    scan_kernel<<<KT, 256, 0, stream>>>(deg, offs, cursor);
    scatter_kernel<<<(net + 255) / 256, 256, 0, stream>>>(ei, ea, cursor, se);

    SplitJobs jobs;
    int maxtot = 0;
    for (int l = 0; l < 3; ++l) {
        int ci  = (l == 0) ? 170 : 256;
        int KP1 = (ci + 31) / 32 * 32;
        int hid = 2 * ci;
        int NHP = (hid + 127) / 128 * 128;
        int KP2 = (hid + 63) / 64 * 64;       // 64-padded (gemm2 NIT even, static count)
        jobs.j[2 * l]     = { (const float*)d_in[3 + 8 * l + 2], bta_l[l], ci,  hid, NHP, KP1 };
        jobs.j[2 * l + 1] = { (const float*)d_in[3 + 8 * l + 6], btb_l[l], hid, 256, 256, KP2 };
        maxtot = max(maxtot, KT * NHP * KP1);
        maxtot = max(maxtot, KT * 256 * KP2);
    }
    dim3 gsp((maxtot + 255) / 256, 1, 6);
    split_all_kernel<<<gsp, 256, 0, stream>>>(jobs);

    const void* hin = x;
    for (int l = 0; l < 3; ++l) {
        int ci  = (l == 0) ? 170 : 256;
        int KP1 = (ci + 31) / 32 * 32;        // 192 / 256
        int hid = 2 * ci;                     // 340 / 512
        int NHP = (hid + 127) / 128 * 128;    // 384 / 512
        int KP2 = (hid + 63) / 64 * 64;       // 384 / 512
        const float* We = (const float*)d_in[3 + 8 * l + 0];
        const float* be = (const float*)d_in[3 + 8 * l + 1];
        const float* ba = (const float*)d_in[3 + 8 * l + 3];
        const float* g  = (const float*)d_in[3 + 8 * l + 4];
        const float* bt = (const float*)d_in[3 + 8 * l + 5];
        const float* bb = (const float*)d_in[3 + 8 * l + 7];

        dim3 ga(NP / 16, KT);
        if (l == 0)
            aggr_kernel<170, false><<<ga, 256, 0, stream>>>(hin, se, offs, We, be, a1_hi);
        else
            aggr_kernel<256, true><<<ga, 256, 0, stream>>>(hin, se, offs, We, be, a1_hi);

        dim3 g1(NHP / 128, NP / 128, KT);
        if (l == 0)
            gemm1_mfma<192><<<g1, 256, 0, stream>>>(a1_hi, bta_l[l], ba, h3, psum, KP2, hid);
        else
            gemm1_mfma<256><<<g1, 256, 0, stream>>>(a1_hi, bta_l[l], ba, h3, psum, KP2, hid);

        dim3 gf(KT, 8);
        finalize_kernel<<<gf, 256, 0, stream>>>(psum, g, bt, scale3, shift3, hid, NHP / 128);

        unsigned short* outb = (l == 0) ? bufA : bufB;
        dim3 g2(2, NP / 64);
        if (l == 0)
            gemm2_mfma<384><<<g2, 256, 0, stream>>>(h3, scale3, shift3, btb_l[l], bb,
                                                    (float*)d_out, outb, hid,
                                                    1, 1);
        else
            gemm2_mfma<512><<<g2, 256, 0, stream>>>(h3, scale3, shift3, btb_l[l], bb,
                                                    (float*)d_out, outb, hid,
                                                    (l < 2) ? 1 : 0, (l < 2) ? 1 : 0);

        hin = (l < 2) ? (const void*)outb : nullptr;
    }
}

// Round 7
// 747.620 us; speedup vs baseline: 1.4895x; 1.0680x over previous
//
#include <hip/hip_runtime.h>
#include <math.h>

#define NN 16500
#define NP 16512      // 129 * 128 padded rows
#define NE 100000
#define KT 3

typedef __attribute__((ext_vector_type(8))) short bf8_t;   // 8 x bf16
typedef __attribute__((ext_vector_type(4))) float f4_t;    // MFMA accumulator

__device__ __forceinline__ unsigned short f2bf(float f) {
    unsigned int u = __float_as_uint(f);
    u += 0x7fffu + ((u >> 16) & 1u);   // RNE
    return (unsigned short)(u >> 16);
}
__device__ __forceinline__ float bf2f(unsigned short h) {
    return __uint_as_float(((unsigned int)h) << 16);
}
__device__ __forceinline__ void gload16(unsigned short* lds, const unsigned short* g) {
    __builtin_amdgcn_global_load_lds(
        (const __attribute__((address_space(1))) void*)g,
        (__attribute__((address_space(3))) void*)lds, 16, 0, 0);
}

// ---------------- CSR build ----------------

__global__ void deg_kernel(const int* __restrict__ ei, int* __restrict__ deg) {
    int t = blockIdx.x * blockDim.x + threadIdx.x;
    if (t >= KT * NE) return;
    int k = t / NE, e = t - k * NE;
    int d = ei[k * 2 * NE + NE + e];
    atomicAdd(&deg[k * NN + d], 1);
}

__global__ void scan_kernel(const int* __restrict__ deg, int* __restrict__ offs,
                            int* __restrict__ cursor) {
    int k = blockIdx.x;
    const int* dg = deg + k * NN;
    int* of = offs + k * (NN + 1);
    int* cu = cursor + k * NN;
    __shared__ int part[256];
    int tid = threadIdx.x;
    const int chunk = (NN + 255) / 256;
    int s0 = tid * chunk, s1 = min(NN, s0 + chunk);
    if (s0 > s1) s0 = s1;
    int sum = 0;
    for (int i = s0; i < s1; ++i) sum += dg[i];
    part[tid] = sum;
    __syncthreads();
    for (int off = 1; off < 256; off <<= 1) {
        int v = part[tid];
        int vp = (tid >= off) ? part[tid - off] : 0;
        __syncthreads();
        part[tid] = v + vp;
        __syncthreads();
    }
    int run = (tid == 0) ? 0 : part[tid - 1];
    for (int i = s0; i < s1; ++i) {
        of[i] = run; cu[i] = run;
        run += dg[i];
    }
    if (tid == 255) of[NN] = run;
}

__global__ void scatter_kernel(const int* __restrict__ ei, const float* __restrict__ ea,
                               int* __restrict__ cursor, int2* __restrict__ se) {
    int t = blockIdx.x * blockDim.x + threadIdx.x;
    if (t >= KT * NE) return;
    int k = t / NE, e = t - k * NE;
    int s = ei[k * 2 * NE + e];
    int d = ei[k * 2 * NE + NE + e];
    float a = ea[(size_t)k * NE + e];
    int pos = atomicAdd(&cursor[k * NN + d], 1);
    int2 p; p.x = s; p.y = __float_as_int(a);
    se[(size_t)k * NE + pos] = p;
}

// ---------------- softmax aggregation (unchanged) ----------------

template<int CI, bool BF16X>
__device__ __forceinline__ void loadrow4(float out[4], const void* xv, int s, int c0) {
    if (BF16X) {
        const unsigned short* xb = (const unsigned short*)xv;
        uint2 u = *(const uint2*)(xb + (size_t)s * CI + c0);
        out[0] = bf2f((unsigned short)(u.x & 0xffffu));
        out[1] = bf2f((unsigned short)(u.x >> 16));
        out[2] = bf2f((unsigned short)(u.y & 0xffffu));
        out[3] = bf2f((unsigned short)(u.y >> 16));
    } else {
        const float* p = (const float*)xv + (size_t)s * CI + c0;
        if (c0 + 4 <= CI) {
            float2 ab = *(const float2*)p;
            float2 cd = *(const float2*)(p + 2);
            out[0] = ab.x; out[1] = ab.y; out[2] = cd.x; out[3] = cd.y;
        } else {
            #pragma unroll
            for (int e = 0; e < 4; ++e) out[e] = (c0 + e < CI) ? p[e] : 0.f;
        }
    }
}

template<int CI, bool BF16X>
__global__ __launch_bounds__(256) void aggr_kernel(
    const void* __restrict__ xv, const int2* __restrict__ se_all,
    const int* __restrict__ offs_all,
    const float* __restrict__ We_all, const float* __restrict__ be_all,
    unsigned short* __restrict__ out_hi)
{
    constexpr int KP = (CI + 31) / 32 * 32;
    int k = blockIdx.y;
    int wv = threadIdx.x >> 6, lane = threadIdx.x & 63;
    int c0 = lane * 4;
    unsigned short* o = out_hi + (size_t)k * NP * KP;
    const int2*  se   = se_all + (size_t)k * NE;
    const int*   offs = offs_all + k * (NN + 1);
    const float* We   = We_all + (size_t)k * CI;
    const float* be   = be_all + (size_t)k * CI;

    constexpr bool ACT_ALL = (64 * 4 == KP) && (CI == KP);
    bool act = ACT_ALL || (c0 < CI);
    float w[4], b[4];
    #pragma unroll
    for (int e = 0; e < 4; ++e) {
        bool a = (c0 + e) < CI;
        w[e] = a ? We[c0 + e] : 0.f;
        b[e] = a ? be[c0 + e] : 0.f;
    }

    for (int it = 0; it < 4; ++it) {
        int d = blockIdx.x * 16 + it * 4 + wv;
        if (d >= NN) {
            if (c0 < KP) { uint2 z = {0u, 0u}; *(uint2*)(o + (size_t)d * KP + c0) = z; }
            continue;
        }
        float xd[4] = {0.f, 0.f, 0.f, 0.f};
        if (act) loadrow4<CI, BF16X>(xd, xv, d, c0);
        #pragma unroll
        for (int e = 0; e < 4; ++e) if ((c0 + e) >= CI) xd[e] = 0.f;

        float den[4], num[4];
        #pragma unroll
        for (int e = 0; e < 4; ++e) {
            float mg = fmaxf(xd[e] + w[e] + b[e], 0.f);   // self loop, ea=1
            float ex = __expf(mg);
            den[e] = ex;
            num[e] = mg * ex;
        }

        auto step = [&](const float xc[4], float a) {
            #pragma unroll
            for (int e = 0; e < 4; ++e) {
                float t = xc[e] + fmaf(a, w[e], b[e]);
                float mg = fmaxf(t, 0.f);
                float ex = __expf(mg);
                den[e] += ex;
                num[e] = fmaf(mg, ex, num[e]);
            }
        };

        int start = offs[d], end = offs[d + 1];
        for (int base = start; base < end; base += 64) {
            int cnt = min(64, end - base);
            int sv = 0; float av = 0.f;
            if (lane < cnt) {
                int2 p = se[base + lane];
                sv = p.x; av = __int_as_float(p.y);
            }
            float x0[4] = {0.f,0.f,0.f,0.f}, x1[4] = {0.f,0.f,0.f,0.f};
            float x2[4] = {0.f,0.f,0.f,0.f}, x3[4] = {0.f,0.f,0.f,0.f};
            {
                int sA = __shfl(sv, 0), sB = __shfl(sv, 1);
                int sC = __shfl(sv, 2), sD = __shfl(sv, 3);
                if (act)            loadrow4<CI, BF16X>(x0, xv, sA, c0);
                if (act && cnt > 1) loadrow4<CI, BF16X>(x1, xv, sB, c0);
                if (act && cnt > 2) loadrow4<CI, BF16X>(x2, xv, sC, c0);
                if (act && cnt > 3) loadrow4<CI, BF16X>(x3, xv, sD, c0);
            }
            int j = 0;
            for (; j + 3 < cnt; j += 4) {
                float a0 = __shfl(av, j),     a1 = __shfl(av, j + 1);
                float a2 = __shfl(av, j + 2), a3 = __shfl(av, j + 3);
                int s4 = __shfl(sv, (j + 4) & 63), s5 = __shfl(sv, (j + 5) & 63);
                int s6 = __shfl(sv, (j + 6) & 63), s7 = __shfl(sv, (j + 7) & 63);
                step(x0, a0);
                if (act && (j + 4) < cnt) loadrow4<CI, BF16X>(x0, xv, s4, c0);
                step(x1, a1);
                if (act && (j + 5) < cnt) loadrow4<CI, BF16X>(x1, xv, s5, c0);
                step(x2, a2);
                if (act && (j + 6) < cnt) loadrow4<CI, BF16X>(x2, xv, s6, c0);
                step(x3, a3);
                if (act && (j + 7) < cnt) loadrow4<CI, BF16X>(x3, xv, s7, c0);
            }
            if (j < cnt)     step(x0, __shfl(av, j));
            if (j + 1 < cnt) step(x1, __shfl(av, j + 1));
            if (j + 2 < cnt) step(x2, __shfl(av, j + 2));
        }
        if (c0 < KP) {
            unsigned short r[4];
            #pragma unroll
            for (int e = 0; e < 4; ++e) {
                float v = ((c0 + e) < CI) ? (num[e] / den[e] + xd[e]) : 0.f;
                r[e] = f2bf(v);
            }
            uint2 pk = {(unsigned)r[0] | ((unsigned)r[1] << 16),
                        (unsigned)r[2] | ((unsigned)r[3] << 16)};
            *(uint2*)(o + (size_t)d * KP + c0) = pk;
        }
    }
}

// ---------------- weight split+transpose ----------------

struct SplitJob { const float* W; unsigned short* out; int kdim, ndim, np_, kp; };
struct SplitJobs { SplitJob j[6]; };

__global__ void split_all_kernel(SplitJobs jobs) {
    SplitJob jb = jobs.j[blockIdx.z];
    int idx = blockIdx.x * 256 + threadIdx.x;
    int total = KT * jb.np_ * jb.kp;
    if (idx >= total) return;
    int k = idx / (jb.np_ * jb.kp);
    int rem = idx - k * jb.np_ * jb.kp;
    int n = rem / jb.kp;
    int kk = rem - n * jb.kp;
    float v = (n < jb.ndim && kk < jb.kdim) ? jb.W[((size_t)k * jb.kdim + kk) * jb.ndim + n] : 0.f;
    jb.out[idx] = f2bf(v);
}

// ---------------- PASS 1: gemm1 stats-only (dbuf, round-3 structure, no C write) ----------------
// h = A@Wa + ba computed in fp32 accumulators; only per-channel partial sums s1,s2 are
// written (tiny psum). BN stats are thus on fp32 h, matching the reference closer than
// the old quantized-h stats.

__global__ __launch_bounds__(256, 3) void gemm1_stats(
    const unsigned short* __restrict__ A_hi,
    const unsigned short* __restrict__ B_hi,
    const float* __restrict__ bias_all,
    float* __restrict__ psum,
    int KP, int Nv)
{
    __shared__ unsigned short Ah[2][128 * 32];
    __shared__ unsigned short Bh[2][128 * 32];

    int z = blockIdx.z;
    int gxT = gridDim.x, gyT = gridDim.y;
    int NHP = gxT * 128;
    const unsigned short* Ahg = A_hi + (size_t)z * NP * KP;
    const unsigned short* Bhg = B_hi + (size_t)z * NHP * KP;
    const float* bias = bias_all + (size_t)z * Nv;

    int tid = threadIdx.x;
    int w = tid >> 6, l = tid & 63;
    int bm = blockIdx.y * 128, bn = blockIdx.x * 128;
    int lane15 = l & 15, quad = l >> 4;
    int wm = (w >> 1) * 64, wn = (w & 1) * 64;
    int srow = l & 15;
    int scol = (l >> 4) * 8;

    f4_t acc[4][4];
    #pragma unroll
    for (int i = 0; i < 4; ++i)
        #pragma unroll
        for (int j = 0; j < 4; ++j) { f4_t zz = {0.f,0.f,0.f,0.f}; acc[i][j] = zz; }

    size_t aoff0 = (size_t)(bm + 32 * w +  0 + srow) * KP + scol;
    size_t aoff1 = (size_t)(bm + 32 * w + 16 + srow) * KP + scol;
    size_t boff0 = (size_t)(bn + 32 * w +  0 + srow) * KP + scol;
    size_t boff1 = (size_t)(bn + 32 * w + 16 + srow) * KP + scol;
    int rb0 = 32 * w, rb1 = 32 * w + 16;
    int ta = (w >> 1) * 4, tb = (w & 1) * 4;

    gload16(&Ah[0][rb0 * 32], Ahg + aoff0);
    gload16(&Ah[0][rb1 * 32], Ahg + aoff1);
    gload16(&Bh[0][rb0 * 32], Bhg + boff0);
    gload16(&Bh[0][rb1 * 32], Bhg + boff1);
    __syncthreads();

    int cur = 0;
    for (int k0 = 32; k0 < KP; k0 += 32) {
        int nxt = cur ^ 1;
        gload16(&Ah[nxt][rb0 * 32], Ahg + aoff0 + k0);
        gload16(&Ah[nxt][rb1 * 32], Ahg + aoff1 + k0);
        gload16(&Bh[nxt][rb0 * 32], Bhg + boff0 + k0);
        gload16(&Bh[nxt][rb1 * 32], Bhg + boff1 + k0);

        bf8_t fa[4], fb[4];
        #pragma unroll
        for (int i = 0; i < 4; ++i) {
            fa[i] = *(const bf8_t*)&Ah[cur][(ta + i) * 512 + l * 8];
            fb[i] = *(const bf8_t*)&Bh[cur][(tb + i) * 512 + l * 8];
        }
        #pragma unroll
        for (int i = 0; i < 4; ++i)
            #pragma unroll
            for (int j = 0; j < 4; ++j)
                acc[i][j] = __builtin_amdgcn_mfma_f32_16x16x32_bf16(fa[i], fb[j], acc[i][j], 0, 0, 0);
        __syncthreads();
        cur = nxt;
    }
    {
        bf8_t fa[4], fb[4];
        #pragma unroll
        for (int i = 0; i < 4; ++i) {
            fa[i] = *(const bf8_t*)&Ah[cur][(ta + i) * 512 + l * 8];
            fb[i] = *(const bf8_t*)&Bh[cur][(tb + i) * 512 + l * 8];
        }
        #pragma unroll
        for (int i = 0; i < 4; ++i)
            #pragma unroll
            for (int j = 0; j < 4; ++j)
                acc[i][j] = __builtin_amdgcn_mfma_f32_16x16x32_bf16(fa[i], fb[j], acc[i][j], 0, 0, 0);
    }

    // epilogue: fp32 BN partial stats only
    #pragma unroll
    for (int j = 0; j < 4; ++j) {
        int c = bn + wn + j * 16 + lane15;
        float bc = (c < Nv) ? bias[c] : 0.f;
        float s1 = 0.f, s2 = 0.f;
        #pragma unroll
        for (int i = 0; i < 4; ++i) {
            #pragma unroll
            for (int r5 = 0; r5 < 4; ++r5) {
                int r = bm + wm + i * 16 + quad * 4 + r5;
                bool ok = (r < NN) && (c < Nv);
                float v = ok ? (acc[i][j][r5] + bc) : 0.f;
                s1 += v;
                s2 = fmaf(v, v, s2);
            }
        }
        s1 += __shfl_xor(s1, 16); s2 += __shfl_xor(s2, 16);
        s1 += __shfl_xor(s1, 32); s2 += __shfl_xor(s2, 32);
        if (quad == 0) {
            int wrow = w >> 1;
            int col = wn + j * 16 + lane15;
            size_t o = ((((size_t)z * gyT + blockIdx.y) * gxT + blockIdx.x) * 2 + wrow) * 256 + col * 2;
            float2 st = {s1, s2};
            *(float2*)&psum[o] = st;
        }
    }
}

// ---------------- finalize BN scale/shift from partials ----------------

__global__ __launch_bounds__(256) void finalize_kernel(
    const float* __restrict__ psum,
    const float* __restrict__ g_all, const float* __restrict__ bt_all,
    float* __restrict__ scale_all, float* __restrict__ shift_all,
    int hid, int gxT)
{
    int z = blockIdx.x;
    int t64 = threadIdx.x & 63;
    int slice = threadIdx.x >> 6;          // 0..3 gy-slices
    int c = blockIdx.y * 64 + t64;         // channel
    __shared__ double rs1[4][64];
    __shared__ double rs2[4][64];
    double s1 = 0.0, s2 = 0.0;
    if (c < gxT * 128) {
        int gx = c >> 7, col = c & 127;
        for (int gy = slice; gy < NP / 128; gy += 4) {
            size_t base = (((size_t)z * (NP / 128) + gy) * gxT + gx) * 2 * 256 + col * 2;
            float2 a  = *(const float2*)&psum[base];
            float2 b2 = *(const float2*)&psum[base + 256];
            s1 += (double)a.x + b2.x;
            s2 += (double)a.y + b2.y;
        }
    }
    rs1[slice][t64] = s1;
    rs2[slice][t64] = s2;
    __syncthreads();
    if (slice == 0 && c < hid) {
        double S1 = rs1[0][t64] + rs1[1][t64] + rs1[2][t64] + rs1[3][t64];
        double S2 = rs2[0][t64] + rs2[1][t64] + rs2[2][t64] + rs2[3][t64];
        double mu = S1 / NN;
        double var = S2 / NN - mu * mu;
        if (var < 0.0) var = 0.0;
        float rs = (float)(1.0 / sqrt(var + 1e-5));
        float sc = rs * g_all[(size_t)z * hid + c];
        scale_all[(size_t)z * 512 + c] = sc;
        shift_all[(size_t)z * 512 + c] = bt_all[(size_t)z * hid + c] - (float)mu * sc;
    }
}

// ---------------- PASS 2: fused gemm1 -> BN+ReLU -> gemm2, z-folded, h never global -----------
// 64-row blocks (258). Per z: A tile staged once (frag-major LDS). Per 128-col hid-slice:
//   gemm1 phase: waves col-partition the slice (wave w: cols w*32..+32), so each weight
//     fragment is read once per BLOCK (direct 16B L2-hot loads); A-frags from LDS.
//   bounce: +ba, BN, ReLU, bf16 -> Hb[s&1] (row-major, stride 130 shorts => conflict-free
//     frag reads: bank(lane) = (33*lane15 + 4*quad) % 32, <=2-way).
//   barrier, gemm2 phase: waves col-partition the 256 output cols; out-acc fp32 persists
//     across slices AND z (link-type sum folded); Wb frags direct 16B.
// One barrier per slice; Hb double-buffered (write slot s&1, read after barrier; next
// write to same slot is separated by two barriers). Epilogue: +sum(bias), leaky, store.

template<int KP1, int HP>
__global__ __launch_bounds__(256, 2) void fused_mid(
    const unsigned short* __restrict__ a1,     // [KT][NP][KP1] bf16
    const unsigned short* __restrict__ Wat,    // [KT][HP][KP1] bf16 (bta)
    const unsigned short* __restrict__ Wbt,    // [KT][256][HP] bf16 (btb)
    const float* __restrict__ ba_all,          // [KT][hid]
    const float* __restrict__ scale_all,       // [KT][512]
    const float* __restrict__ shift_all,       // [KT][512]
    const float* __restrict__ bb,              // [KT][256]
    float* __restrict__ outf, unsigned short* __restrict__ outb,
    int hid, int leaky, int as_bf16)
{
    constexpr int NKS = KP1 / 32;
    constexpr int NSL = HP / 128;
    __shared__ unsigned short Ah[NKS * 4 * 512];
    __shared__ unsigned short Hb[2][64 * 130];

    int tid = threadIdx.x, w = tid >> 6, l = tid & 63;
    int lane15 = l & 15, quad = l >> 4;
    int bm = blockIdx.x * 64;

    f4_t outacc[4][4];   // [rb 16-row block][jc col-frag], cols 64w + jc*16
    #pragma unroll
    for (int i = 0; i < 4; ++i)
        #pragma unroll
        for (int j = 0; j < 4; ++j) { f4_t zz = {0.f,0.f,0.f,0.f}; outacc[i][j] = zz; }

    for (int z = 0; z < KT; ++z) {
        const unsigned short* Az  = a1  + (size_t)z * NP * KP1;
        const unsigned short* Waz = Wat + (size_t)z * HP * KP1;
        const unsigned short* Wbz = Wbt + (size_t)z * 256 * HP;
        const float* scl = scale_all + z * 512;
        const float* shf = shift_all + z * 512;
        const float* baz = ba_all + (size_t)z * hid;

        // stage A tile (64 x KP1), fragment-major: subtile (ks, rowhalf w), lane's 16B
        #pragma unroll
        for (int ks = 0; ks < NKS; ++ks)
            gload16(&Ah[(ks * 4 + w) * 512 + l * 8],
                    Az + (size_t)(bm + 16 * w + lane15) * KP1 + ks * 32 + quad * 8);
        __syncthreads();   // drains DMA (vmcnt0) + publishes; prior-z Ah reads all
                           // completed before the last slice's mid-barrier.

        #pragma unroll
        for (int s = 0; s < NSL; ++s) {
            int c2w = s * 128 + w * 32;    // wave's gemm1 col base
            // ---- gemm1 phase: h[64 rows][32 cols] for this wave ----
            f4_t hacc[4][2];
            #pragma unroll
            for (int i = 0; i < 4; ++i)
                #pragma unroll
                for (int j = 0; j < 2; ++j) { f4_t zz = {0.f,0.f,0.f,0.f}; hacc[i][j] = zz; }
            #pragma unroll
            for (int ks = 0; ks < NKS; ++ks) {
                bf8_t wa0 = *(const bf8_t*)(Waz + (size_t)(c2w + lane15) * KP1 + ks * 32 + quad * 8);
                bf8_t wa1 = *(const bf8_t*)(Waz + (size_t)(c2w + 16 + lane15) * KP1 + ks * 32 + quad * 8);
                #pragma unroll
                for (int rb = 0; rb < 4; ++rb) {
                    bf8_t af = *(const bf8_t*)&Ah[(ks * 4 + rb) * 512 + l * 8];
                    hacc[rb][0] = __builtin_amdgcn_mfma_f32_16x16x32_bf16(af, wa0, hacc[rb][0], 0, 0, 0);
                    hacc[rb][1] = __builtin_amdgcn_mfma_f32_16x16x32_bf16(af, wa1, hacc[rb][1], 0, 0, 0);
                }
            }
            // ---- +ba, BN, ReLU, bf16 -> Hb[s&1] ----
            unsigned short* hb = &Hb[s & 1][0];
            #pragma unroll
            for (int jn = 0; jn < 2; ++jn) {
                int c2 = c2w + jn * 16 + lane15;
                bool okc = c2 < hid;
                float bax = okc ? baz[c2] : 0.f;
                float sc  = okc ? scl[c2] : 0.f;
                float sh  = okc ? shf[c2] : 0.f;
                int colw = w * 32 + jn * 16 + lane15;   // col within 128-slice
                #pragma unroll
                for (int rb = 0; rb < 4; ++rb)
                    #pragma unroll
                    for (int r5 = 0; r5 < 4; ++r5) {
                        float v = fmaxf(fmaf(hacc[rb][jn][r5] + bax, sc, sh), 0.f);
                        int row = rb * 16 + quad * 4 + r5;
                        hb[row * 130 + colw] = f2bf(v);
                    }
            }
            __syncthreads();   // all waves' slice writes visible
            // ---- gemm2 phase: out[64 rows][cols 64w..+64] += Hslice @ Wb[slice] ----
            #pragma unroll
            for (int t = 0; t < 4; ++t) {
                bf8_t hf[4];
                #pragma unroll
                for (int rb = 0; rb < 4; ++rb)
                    hf[rb] = *(const bf8_t*)&hb[(rb * 16 + lane15) * 130 + t * 32 + quad * 8];
                #pragma unroll
                for (int jc = 0; jc < 4; ++jc) {
                    bf8_t wb = *(const bf8_t*)(Wbz + (size_t)(64 * w + jc * 16 + lane15) * HP
                                               + s * 128 + t * 32 + quad * 8);
                    #pragma unroll
                    for (int rb = 0; rb < 4; ++rb)
                        outacc[rb][jc] = __builtin_amdgcn_mfma_f32_16x16x32_bf16(hf[rb], wb, outacc[rb][jc], 0, 0, 0);
                }
            }
            // no barrier here: next slice writes the OTHER Hb slot; a write that wraps
            // back to this slot is separated from these reads by two barriers.
        }
    }

    // ---- epilogue: + sum-of-biases over z, leaky, store ----
    #pragma unroll
    for (int jc = 0; jc < 4; ++jc) {
        int c = 64 * w + jc * 16 + lane15;
        float bsum = bb[c] + bb[256 + c] + bb[512 + c];
        #pragma unroll
        for (int rb = 0; rb < 4; ++rb)
            #pragma unroll
            for (int r5 = 0; r5 < 4; ++r5) {
                int r = bm + rb * 16 + quad * 4 + r5;
                if (r < NN) {
                    float v = outacc[rb][jc][r5] + bsum;
                    if (leaky) v = (v > 0.f) ? v : 0.01f * v;
                    if (as_bf16) outb[(size_t)r * 256 + c] = f2bf(v);
                    else         outf[(size_t)r * 256 + c] = v;
                }
            }
    }
}

// ---------------- host ----------------

extern "C" void kernel_launch(void* const* d_in, const int* in_sizes, int n_in,
                              void* d_out, int out_size, void* d_ws, size_t ws_size,
                              hipStream_t stream)
{
    const float* x  = (const float*)d_in[0];
    const int*   ei = (const int*)d_in[1];
    const float* ea = (const float*)d_in[2];

    char* w = (char*)d_ws;
    auto alloc = [&](size_t bytes) {
        char* p = w;
        w += (bytes + 255) & ~(size_t)255;
        return p;
    };
    int* deg    = (int*)alloc((size_t)KT * NN * 4);
    int* offs   = (int*)alloc((size_t)KT * (NN + 1) * 4);
    int* cursor = (int*)alloc((size_t)KT * NN * 4);
    int2* se    = (int2*)alloc((size_t)KT * NE * 8);
    unsigned short* a1_hi = (unsigned short*)alloc((size_t)KT * NP * 256 * 2);
    unsigned short* bta_l[3];
    unsigned short* btb_l[3];
    for (int l = 0; l < 3; ++l) {
        bta_l[l] = (unsigned short*)alloc((size_t)KT * 512 * 256 * 2);
        btb_l[l] = (unsigned short*)alloc((size_t)KT * 256 * 512 * 2);
    }
    float* psum = (float*)alloc((size_t)KT * (NP / 128) * 4 * 2 * 256 * 4);
    float* scale3 = (float*)alloc((size_t)KT * 512 * 4);
    float* shift3 = (float*)alloc((size_t)KT * 512 * 4);
    unsigned short* bufA = (unsigned short*)alloc((size_t)NN * 256 * 2);
    unsigned short* bufB = (unsigned short*)alloc((size_t)NN * 256 * 2);

    hipMemsetAsync(deg, 0, (size_t)KT * NN * 4, stream);
    int net = KT * NE;
    deg_kernel<<<(net + 255) / 256, 256, 0, stream>>>(ei, deg);
    scan_kernel<<<KT, 256, 0, stream>>>(deg, offs, cursor);
    scatter_kernel<<<(net + 255) / 256, 256, 0, stream>>>(ei, ea, cursor, se);

    SplitJobs jobs;
    int maxtot = 0;
    for (int l = 0; l < 3; ++l) {
        int ci  = (l == 0) ? 170 : 256;
        int KP1 = (ci + 31) / 32 * 32;
        int hid = 2 * ci;
        int NHP = (hid + 127) / 128 * 128;    // 384 / 512 == HP
        int KP2 = NHP;                        // btb k-dim padded to HP
        jobs.j[2 * l]     = { (const float*)d_in[3 + 8 * l + 2], bta_l[l], ci,  hid, NHP, KP1 };
        jobs.j[2 * l + 1] = { (const float*)d_in[3 + 8 * l + 6], btb_l[l], hid, 256, 256, KP2 };
        maxtot = max(maxtot, KT * NHP * KP1);
        maxtot = max(maxtot, KT * 256 * KP2);
    }
    dim3 gsp((maxtot + 255) / 256, 1, 6);
    split_all_kernel<<<gsp, 256, 0, stream>>>(jobs);

    const void* hin = x;
    for (int l = 0; l < 3; ++l) {
        int ci  = (l == 0) ? 170 : 256;
        int KP1 = (ci + 31) / 32 * 32;        // 192 / 256
        int hid = 2 * ci;                     // 340 / 512
        int NHP = (hid + 127) / 128 * 128;    // 384 / 512
        const float* We = (const float*)d_in[3 + 8 * l + 0];
        const float* be = (const float*)d_in[3 + 8 * l + 1];
        const float* ba = (const float*)d_in[3 + 8 * l + 3];
        const float* g  = (const float*)d_in[3 + 8 * l + 4];
        const float* bt = (const float*)d_in[3 + 8 * l + 5];
        const float* bb = (const float*)d_in[3 + 8 * l + 7];

        dim3 ga(NP / 16, KT);
        if (l == 0)
            aggr_kernel<170, false><<<ga, 256, 0, stream>>>(hin, se, offs, We, be, a1_hi);
        else
            aggr_kernel<256, true><<<ga, 256, 0, stream>>>(hin, se, offs, We, be, a1_hi);

        dim3 g1(NHP / 128, NP / 128, KT);
        gemm1_stats<<<g1, 256, 0, stream>>>(a1_hi, bta_l[l], ba, psum, KP1, hid);

        dim3 gf(KT, 8);
        finalize_kernel<<<gf, 256, 0, stream>>>(psum, g, bt, scale3, shift3, hid, NHP / 128);

        unsigned short* outb = (l == 0) ? bufA : bufB;
        if (l == 0)
            fused_mid<192, 384><<<NP / 64, 256, 0, stream>>>(
                a1_hi, bta_l[l], btb_l[l], ba, scale3, shift3, bb,
                (float*)d_out, outb, hid, 1, 1);
        else
            fused_mid<256, 512><<<NP / 64, 256, 0, stream>>>(
                a1_hi, bta_l[l], btb_l[l], ba, scale3, shift3, bb,
                (float*)d_out, outb, hid, (l < 2) ? 1 : 0, (l < 2) ? 1 : 0);

        hin = (l < 2) ? (const void*)outb : nullptr;
    }
}

// Round 10
// 652.844 us; speedup vs baseline: 1.7057x; 1.1452x over previous
//
#include <hip/hip_runtime.h>
#include <math.h>

#define NN 16500
#define NP 16512      // 129 * 128 padded rows
#define NE 100000
#define KT 3

typedef __attribute__((ext_vector_type(8))) short bf8_t;   // 8 x bf16
typedef __attribute__((ext_vector_type(4))) float f4_t;    // MFMA accumulator

__device__ __forceinline__ unsigned short f2bf(float f) {
    unsigned int u = __float_as_uint(f);
    u += 0x7fffu + ((u >> 16) & 1u);   // RNE
    return (unsigned short)(u >> 16);
}
__device__ __forceinline__ float bf2f(unsigned short h) {
    return __uint_as_float(((unsigned int)h) << 16);
}
__device__ __forceinline__ void gload16(unsigned short* lds, const unsigned short* g) {
    __builtin_amdgcn_global_load_lds(
        (const __attribute__((address_space(1))) void*)g,
        (__attribute__((address_space(3))) void*)lds, 16, 0, 0);
}

// ---------------- CSR build ----------------

__global__ void deg_kernel(const int* __restrict__ ei, int* __restrict__ deg) {
    int t = blockIdx.x * blockDim.x + threadIdx.x;
    if (t >= KT * NE) return;
    int k = t / NE, e = t - k * NE;
    int d = ei[k * 2 * NE + NE + e];
    atomicAdd(&deg[k * NN + d], 1);
}

__global__ void scan_kernel(const int* __restrict__ deg, int* __restrict__ offs,
                            int* __restrict__ cursor) {
    int k = blockIdx.x;
    const int* dg = deg + k * NN;
    int* of = offs + k * (NN + 1);
    int* cu = cursor + k * NN;
    __shared__ int part[256];
    int tid = threadIdx.x;
    const int chunk = (NN + 255) / 256;
    int s0 = tid * chunk, s1 = min(NN, s0 + chunk);
    if (s0 > s1) s0 = s1;
    int sum = 0;
    for (int i = s0; i < s1; ++i) sum += dg[i];
    part[tid] = sum;
    __syncthreads();
    for (int off = 1; off < 256; off <<= 1) {
        int v = part[tid];
        int vp = (tid >= off) ? part[tid - off] : 0;
        __syncthreads();
        part[tid] = v + vp;
        __syncthreads();
    }
    int run = (tid == 0) ? 0 : part[tid - 1];
    for (int i = s0; i < s1; ++i) {
        of[i] = run; cu[i] = run;
        run += dg[i];
    }
    if (tid == 255) of[NN] = run;
}

// scatter edge (src, ea) pairs directly in CSR order — removes one dependent
// gather level from the aggregation critical path.
__global__ void scatter_kernel(const int* __restrict__ ei, const float* __restrict__ ea,
                               int* __restrict__ cursor, int2* __restrict__ se) {
    int t = blockIdx.x * blockDim.x + threadIdx.x;
    if (t >= KT * NE) return;
    int k = t / NE, e = t - k * NE;
    int s = ei[k * 2 * NE + e];
    int d = ei[k * 2 * NE + NE + e];
    float a = ea[(size_t)k * NE + e];
    int pos = atomicAdd(&cursor[k * NN + d], 1);
    int2 p; p.x = s; p.y = __float_as_int(a);
    se[(size_t)k * NE + pos] = p;
}

// ---------------- softmax aggregation: one wave per (dst,k), 4 dsts/wave, depth-4 pipeline ----
// No-max online softmax: msg = relu(x_src + a*We + be) is bounded well below the
// fp32 exp overflow point for this BN-normalized pipeline, so we accumulate
// den = sum exp(msg), num = sum msg*exp(msg) directly.

template<int CI, bool BF16X>
__device__ __forceinline__ void loadrow4(float out[4], const void* xv, int s, int c0) {
    if (BF16X) {
        const unsigned short* xb = (const unsigned short*)xv;
        uint2 u = *(const uint2*)(xb + (size_t)s * CI + c0);
        out[0] = bf2f((unsigned short)(u.x & 0xffffu));
        out[1] = bf2f((unsigned short)(u.x >> 16));
        out[2] = bf2f((unsigned short)(u.y & 0xffffu));
        out[3] = bf2f((unsigned short)(u.y >> 16));
    } else {
        const float* p = (const float*)xv + (size_t)s * CI + c0;
        if (c0 + 4 <= CI) {
            float2 ab = *(const float2*)p;
            float2 cd = *(const float2*)(p + 2);
            out[0] = ab.x; out[1] = ab.y; out[2] = cd.x; out[3] = cd.y;
        } else {
            #pragma unroll
            for (int e = 0; e < 4; ++e) out[e] = (c0 + e < CI) ? p[e] : 0.f;
        }
    }
}

template<int CI, bool BF16X>
__global__ __launch_bounds__(256) void aggr_kernel(
    const void* __restrict__ xv, const int2* __restrict__ se_all,
    const int* __restrict__ offs_all,
    const float* __restrict__ We_all, const float* __restrict__ be_all,
    unsigned short* __restrict__ out_hi)
{
    constexpr int KP = (CI + 31) / 32 * 32;
    int k = blockIdx.y;
    int wv = threadIdx.x >> 6, lane = threadIdx.x & 63;
    int c0 = lane * 4;
    unsigned short* o = out_hi + (size_t)k * NP * KP;
    const int2*  se   = se_all + (size_t)k * NE;
    const int*   offs = offs_all + k * (NN + 1);
    const float* We   = We_all + (size_t)k * CI;
    const float* be   = be_all + (size_t)k * CI;

    constexpr bool ACT_ALL = (64 * 4 == KP) && (CI == KP);
    bool act = ACT_ALL || (c0 < CI);
    float w[4], b[4];
    #pragma unroll
    for (int e = 0; e < 4; ++e) {
        bool a = (c0 + e) < CI;
        w[e] = a ? We[c0 + e] : 0.f;
        b[e] = a ? be[c0 + e] : 0.f;
    }

    for (int it = 0; it < 4; ++it) {
        int d = blockIdx.x * 16 + it * 4 + wv;
        if (d >= NN) {
            if (c0 < KP) { uint2 z = {0u, 0u}; *(uint2*)(o + (size_t)d * KP + c0) = z; }
            continue;
        }
        float xd[4] = {0.f, 0.f, 0.f, 0.f};
        if (act) loadrow4<CI, BF16X>(xd, xv, d, c0);
        #pragma unroll
        for (int e = 0; e < 4; ++e) if ((c0 + e) >= CI) xd[e] = 0.f;

        float den[4], num[4];
        #pragma unroll
        for (int e = 0; e < 4; ++e) {
            float mg = fmaxf(xd[e] + w[e] + b[e], 0.f);   // self loop, ea=1
            float ex = __expf(mg);
            den[e] = ex;
            num[e] = mg * ex;
        }

        auto step = [&](const float xc[4], float a) {
            #pragma unroll
            for (int e = 0; e < 4; ++e) {
                float t = xc[e] + fmaf(a, w[e], b[e]);
                float mg = fmaxf(t, 0.f);
                float ex = __expf(mg);
                den[e] += ex;
                num[e] = fmaf(mg, ex, num[e]);
            }
        };

        int start = offs[d], end = offs[d + 1];
        for (int base = start; base < end; base += 64) {
            int cnt = min(64, end - base);
            int sv = 0; float av = 0.f;
            if (lane < cnt) {
                int2 p = se[base + lane];
                sv = p.x; av = __int_as_float(p.y);
            }
            float x0[4] = {0.f,0.f,0.f,0.f}, x1[4] = {0.f,0.f,0.f,0.f};
            float x2[4] = {0.f,0.f,0.f,0.f}, x3[4] = {0.f,0.f,0.f,0.f};
            {
                int sA = __shfl(sv, 0), sB = __shfl(sv, 1);
                int sC = __shfl(sv, 2), sD = __shfl(sv, 3);
                if (act)            loadrow4<CI, BF16X>(x0, xv, sA, c0);
                if (act && cnt > 1) loadrow4<CI, BF16X>(x1, xv, sB, c0);
                if (act && cnt > 2) loadrow4<CI, BF16X>(x2, xv, sC, c0);
                if (act && cnt > 3) loadrow4<CI, BF16X>(x3, xv, sD, c0);
            }
            int j = 0;
            for (; j + 3 < cnt; j += 4) {
                float a0 = __shfl(av, j),     a1 = __shfl(av, j + 1);
                float a2 = __shfl(av, j + 2), a3 = __shfl(av, j + 3);
                int s4 = __shfl(sv, (j + 4) & 63), s5 = __shfl(sv, (j + 5) & 63);
                int s6 = __shfl(sv, (j + 6) & 63), s7 = __shfl(sv, (j + 7) & 63);
                step(x0, a0);
                if (act && (j + 4) < cnt) loadrow4<CI, BF16X>(x0, xv, s4, c0);
                step(x1, a1);
                if (act && (j + 5) < cnt) loadrow4<CI, BF16X>(x1, xv, s5, c0);
                step(x2, a2);
                if (act && (j + 6) < cnt) loadrow4<CI, BF16X>(x2, xv, s6, c0);
                step(x3, a3);
                if (act && (j + 7) < cnt) loadrow4<CI, BF16X>(x3, xv, s7, c0);
            }
            if (j < cnt)     step(x0, __shfl(av, j));
            if (j + 1 < cnt) step(x1, __shfl(av, j + 1));
            if (j + 2 < cnt) step(x2, __shfl(av, j + 2));
        }
        if (c0 < KP) {
            unsigned short r[4];
            #pragma unroll
            for (int e = 0; e < 4; ++e) {
                float v = ((c0 + e) < CI) ? (num[e] / den[e] + xd[e]) : 0.f;
                r[e] = f2bf(v);
            }
            uint2 pk = {(unsigned)r[0] | ((unsigned)r[1] << 16),
                        (unsigned)r[2] | ((unsigned)r[3] << 16)};
            *(uint2*)(o + (size_t)d * KP + c0) = pk;
        }
    }
}

// ---------------- weight split+transpose, all 6 jobs in one launch ----------------

struct SplitJob { const float* W; unsigned short* out; int kdim, ndim, np_, kp; };
struct SplitJobs { SplitJob j[6]; };

__global__ void split_all_kernel(SplitJobs jobs) {
    SplitJob jb = jobs.j[blockIdx.z];
    int idx = blockIdx.x * 256 + threadIdx.x;
    int total = KT * jb.np_ * jb.kp;
    if (idx >= total) return;
    int k = idx / (jb.np_ * jb.kp);
    int rem = idx - k * jb.np_ * jb.kp;
    int n = rem / jb.kp;
    int kk = rem - n * jb.kp;
    float v = (n < jb.ndim && kk < jb.kdim) ? jb.W[((size_t)k * jb.kdim + kk) * jb.ndim + n] : 0.f;
    jb.out[idx] = f2bf(v);
}

// ---------------- GEMM1: bf16 MFMA, dbuf K-loop, fused BN stats, LDS-coalesced C store ------
// The MFMA epilogue's natural store pattern is 2B elements at 16-col stride -> ~4.8x HBM
// write amplification (measured: WRITE_SIZE 54-84 MB vs 12-17 ideal). Fix: bounce the
// 128x128 bf16 C tile through LDS (32KB union with the dead Ah/Bh buffers) and store
// row-contiguous uint4 (16B/lane). Double-buffering is via INTEGER offsets into one
// __shared__ array — pointer arrays of LDS addresses don't compile on gfx950
// (addrspacecast static-initializer error, round-8 lesson).

__global__ __launch_bounds__(256, 2) void gemm1_mfma(
    const unsigned short* __restrict__ A_hi,
    const unsigned short* __restrict__ B_hi,
    const float* __restrict__ bias_all, unsigned short* __restrict__ C_all,
    float* __restrict__ psum,
    int KP, int ldc, int Mv, int Nv)
{
    __shared__ unsigned short smem[16384];   // A dbuf [0|4096], B dbuf [8192|12288]; reused as Ct[128][128]

    int z = blockIdx.z;
    int gxT = gridDim.x, gyT = gridDim.y;
    int NHP = gxT * 128;
    const unsigned short* Ahg = A_hi + (size_t)z * NP * KP;
    const unsigned short* Bhg = B_hi + (size_t)z * NHP * KP;
    const float* bias = bias_all + (size_t)z * Nv;
    unsigned short* C = C_all + (size_t)z * NP * ldc;

    int tid = threadIdx.x;
    int w = tid >> 6, l = tid & 63;
    int bm = blockIdx.y * 128, bn = blockIdx.x * 128;
    int lane15 = l & 15, quad = l >> 4;
    int wm = (w >> 1) * 64, wn = (w & 1) * 64;
    int srow = l & 15;
    int scol = (l >> 4) * 8;

    f4_t acc[4][4];
    #pragma unroll
    for (int i = 0; i < 4; ++i)
        #pragma unroll
        for (int j = 0; j < 4; ++j) { f4_t zz = {0.f,0.f,0.f,0.f}; acc[i][j] = zz; }

    size_t aoff0 = (size_t)(bm + 32 * w +  0 + srow) * KP + scol;
    size_t aoff1 = (size_t)(bm + 32 * w + 16 + srow) * KP + scol;
    size_t boff0 = (size_t)(bn + 32 * w +  0 + srow) * KP + scol;
    size_t boff1 = (size_t)(bn + 32 * w + 16 + srow) * KP + scol;
    int rb0 = 32 * w, rb1 = 32 * w + 16;
    int ta = (w >> 1) * 4, tb = (w & 1) * 4;

    // prologue: stage tile 0 into offset 0
    gload16(&smem[0 + rb0 * 32], Ahg + aoff0);
    gload16(&smem[0 + rb1 * 32], Ahg + aoff1);
    gload16(&smem[8192 + rb0 * 32], Bhg + boff0);
    gload16(&smem[8192 + rb1 * 32], Bhg + boff1);
    __syncthreads();

    int curo = 0;
    for (int k0 = 32; k0 < KP; k0 += 32) {
        int nxto = curo ^ 4096;
        gload16(&smem[nxto + rb0 * 32], Ahg + aoff0 + k0);
        gload16(&smem[nxto + rb1 * 32], Ahg + aoff1 + k0);
        gload16(&smem[8192 + nxto + rb0 * 32], Bhg + boff0 + k0);
        gload16(&smem[8192 + nxto + rb1 * 32], Bhg + boff1 + k0);

        bf8_t fa[4], fb[4];
        #pragma unroll
        for (int i = 0; i < 4; ++i) {
            fa[i] = *(const bf8_t*)&smem[curo + (ta + i) * 512 + l * 8];
            fb[i] = *(const bf8_t*)&smem[8192 + curo + (tb + i) * 512 + l * 8];
        }
        #pragma unroll
        for (int i = 0; i < 4; ++i)
            #pragma unroll
            for (int j = 0; j < 4; ++j)
                acc[i][j] = __builtin_amdgcn_mfma_f32_16x16x32_bf16(fa[i], fb[j], acc[i][j], 0, 0, 0);
        __syncthreads();
        curo = nxto;
    }
    {   // last tile
        bf8_t fa[4], fb[4];
        #pragma unroll
        for (int i = 0; i < 4; ++i) {
            fa[i] = *(const bf8_t*)&smem[curo + (ta + i) * 512 + l * 8];
            fb[i] = *(const bf8_t*)&smem[8192 + curo + (tb + i) * 512 + l * 8];
        }
        #pragma unroll
        for (int i = 0; i < 4; ++i)
            #pragma unroll
            for (int j = 0; j < 4; ++j)
                acc[i][j] = __builtin_amdgcn_mfma_f32_16x16x32_bf16(fa[i], fb[j], acc[i][j], 0, 0, 0);
    }

    __syncthreads();   // all waves done reading staging buffers; safe to reuse as C tile

    // quantize + fused BN partial stats (identical arithmetic to before); C -> LDS
    #pragma unroll
    for (int j = 0; j < 4; ++j) {
        int c = bn + wn + j * 16 + lane15;
        float bc = (c < Nv) ? bias[c] : 0.f;
        float s1 = 0.f, s2 = 0.f;
        #pragma unroll
        for (int i = 0; i < 4; ++i) {
            #pragma unroll
            for (int r5 = 0; r5 < 4; ++r5) {
                int r = bm + wm + i * 16 + quad * 4 + r5;
                float v = acc[i][j][r5] + bc;
                unsigned short q = f2bf(v);
                int lr = wm + i * 16 + quad * 4 + r5;
                int lc = wn + j * 16 + lane15;
                smem[lr * 128 + lc] = q;
                bool ok = (r < NN) && (c < Nv);
                float vq = ok ? bf2f(q) : 0.f;
                s1 += vq;
                s2 = fmaf(vq, vq, s2);
            }
        }
        s1 += __shfl_xor(s1, 16); s2 += __shfl_xor(s2, 16);
        s1 += __shfl_xor(s1, 32); s2 += __shfl_xor(s2, 32);
        if (quad == 0) {
            int wrow = w >> 1;
            int col = wn + j * 16 + lane15;
            size_t o = ((((size_t)z * gyT + blockIdx.y) * gxT + blockIdx.x) * 2 + wrow) * 256 + col * 2;
            float2 st = {s1, s2};
            *(float2*)&psum[o] = st;
        }
    }
    __syncthreads();

    // coalesced C store: 16 lanes x 16B = 256B contiguous per row segment
    int lr8 = tid >> 4;              // row 0..15 base
    int lc8 = (tid & 15) * 8;        // col 0..120
    bool cok = (bn + lc8 + 8) <= ldc;   // l=0 last tile: cols >= ldc don't exist
    if (cok) {
        #pragma unroll
        for (int p = 0; p < 8; ++p) {
            int row = p * 16 + lr8;
            uint4 v = *(const uint4*)&smem[row * 128 + lc8];
            *(uint4*)&C[(size_t)(bm + row) * ldc + bn + lc8] = v;
        }
    }
}

// ---------------- finalize BN scale/shift from partials (parallel over channel chunks) ---------

__global__ __launch_bounds__(256) void finalize_kernel(
    const float* __restrict__ psum,
    const float* __restrict__ g_all, const float* __restrict__ bt_all,
    float* __restrict__ scale_all, float* __restrict__ shift_all,
    int hid, int gxT)
{
    int z = blockIdx.x;
    int t64 = threadIdx.x & 63;
    int slice = threadIdx.x >> 6;          // 0..3 gy-slices
    int c = blockIdx.y * 64 + t64;         // channel
    __shared__ double rs1[4][64];
    __shared__ double rs2[4][64];
    double s1 = 0.0, s2 = 0.0;
    if (c < gxT * 128) {
        int gx = c >> 7, col = c & 127;
        for (int gy = slice; gy < NP / 128; gy += 4) {
            size_t base = (((size_t)z * (NP / 128) + gy) * gxT + gx) * 2 * 256 + col * 2;
            float2 a  = *(const float2*)&psum[base];
            float2 b2 = *(const float2*)&psum[base + 256];
            s1 += (double)a.x + b2.x;
            s2 += (double)a.y + b2.y;
        }
    }
    rs1[slice][t64] = s1;
    rs2[slice][t64] = s2;
    __syncthreads();
    if (slice == 0 && c < hid) {
        double S1 = rs1[0][t64] + rs1[1][t64] + rs1[2][t64] + rs1[3][t64];
        double S2 = rs2[0][t64] + rs2[1][t64] + rs2[2][t64] + rs2[3][t64];
        double mu = S1 / NN;
        double var = S2 / NN - mu * mu;
        if (var < 0.0) var = 0.0;
        float rs = (float)(1.0 / sqrt(var + 1e-5));
        float sc = rs * g_all[(size_t)z * hid + c];
        scale_all[(size_t)z * 512 + c] = sc;
        shift_all[(size_t)z * 512 + c] = bt_all[(size_t)z * hid + c] - (float)mu * sc;
    }
}

// ---------------- GEMM2: k-types folded into K-loop (acc sums over z), dbuf, fused epilogue ----
// 64x128 tile, NIT = 3*KP/32 iters. Round-2 known-good structure (74.6 us/dispatch).

__device__ __forceinline__ bf8_t bnpack(uint4 hv, float4 s0, float4 s1,
                                        float4 t0, float4 t1, int ch0, int hid) {
    unsigned int uu[4] = {hv.x, hv.y, hv.z, hv.w};
    float ss[8] = {s0.x, s0.y, s0.z, s0.w, s1.x, s1.y, s1.z, s1.w};
    float tt[8] = {t0.x, t0.y, t0.z, t0.w, t1.x, t1.y, t1.z, t1.w};
    bf8_t r;
    #pragma unroll
    for (int e = 0; e < 8; ++e) {
        unsigned short hb = (e & 1) ? (unsigned short)(uu[e >> 1] >> 16)
                                    : (unsigned short)(uu[e >> 1] & 0xffffu);
        float x = bf2f(hb);
        float val = (ch0 + e < hid) ? fmaxf(fmaf(x, ss[e], tt[e]), 0.f) : 0.f;
        r[e] = (short)f2bf(val);
    }
    return r;
}

__global__ __launch_bounds__(256, 2) void gemm2_mfma(
    const unsigned short* __restrict__ h_all, const float* __restrict__ scale_all,
    const float* __restrict__ shift_all,
    const unsigned short* __restrict__ B_hi,
    const float* __restrict__ bb,
    float* __restrict__ outf, unsigned short* __restrict__ outb,
    int KP, int hid, int leaky, int as_bf16)
{
    __shared__ unsigned short Ah[2][64 * 32];
    __shared__ unsigned short Bh[2][128 * 32];

    int tid = threadIdx.x;
    int w = tid >> 6, l = tid & 63;
    int bm = blockIdx.y * 64, bn = blockIdx.x * 128;
    int lane15 = l & 15, quad = l >> 4;
    int wm = (w >> 1) * 32, wn = (w & 1) * 64;
    int srow = l & 15, scol = (l >> 4) * 8;

    const int KPZ = KP / 32;
    const int NIT = 3 * KPZ;

    f4_t acc[2][4];
    #pragma unroll
    for (int i = 0; i < 2; ++i)
        #pragma unroll
        for (int j = 0; j < 4; ++j) { f4_t zz = {0.f,0.f,0.f,0.f}; acc[i][j] = zz; }

    int rb0 = 32 * w, rb1 = 32 * w + 16;
    int ta = (w >> 1) * 2, tb = (w & 1) * 4;
    int grow = ((tid >> 6) << 4) + (tid & 15);   // 0..63 A row in tile
    int ccol = ((tid >> 4) & 3) * 8;             // A col offset within k-tile

    size_t arow = (size_t)(bm + grow) * KP + ccol;
    size_t brow0 = (size_t)(bn + 32 * w + srow) * KP + scol;
    size_t brow1 = (size_t)(bn + 32 * w + 16 + srow) * KP + scol;

    // prologue: stage it=0 (z=0, k=0)
    {
        uint4 hv = *(const uint4*)(h_all + arow);
        gload16(&Bh[0][rb0 * 32], B_hi + brow0);
        gload16(&Bh[0][rb1 * 32], B_hi + brow1);
        const float* scl = scale_all + ccol;
        const float* shf = shift_all + ccol;
        float4 s0 = *(const float4*)scl, s1 = *(const float4*)(scl + 4);
        float4 t0 = *(const float4*)shf, t1 = *(const float4*)(shf + 4);
        *(bf8_t*)&Ah[0][tid * 8] = bnpack(hv, s0, s1, t0, t1, ccol, hid);
    }
    __syncthreads();

    int cur = 0;
    for (int it = 0; it < NIT; ++it) {
        int nit = it + 1;
        bool have = nit < NIT;
        int nxt = cur ^ 1;
        uint4 hv;
        float4 s0, s1, t0, t1;
        int nch = 0;
        if (have) {
            int nzz = nit / KPZ, nkk = (nit - nzz * KPZ) * 32;
            nch = nkk + ccol;
            // A-issue first, then B: the A-wait (before bnpack) leaves B gloads in flight
            hv = *(const uint4*)(h_all + (size_t)nzz * NP * KP + arow + nkk);
            const float* scl = scale_all + (size_t)nzz * 512 + nch;
            const float* shf = shift_all + (size_t)nzz * 512 + nch;
            s0 = *(const float4*)scl; s1 = *(const float4*)(scl + 4);
            t0 = *(const float4*)shf; t1 = *(const float4*)(shf + 4);
            const unsigned short* bz = B_hi + (size_t)nzz * 256 * KP + nkk;
            gload16(&Bh[nxt][rb0 * 32], bz + brow0);
            gload16(&Bh[nxt][rb1 * 32], bz + brow1);
        }
        // compute current tile (A-load latency hides here)
        bf8_t fa[2], fb[4];
        #pragma unroll
        for (int i = 0; i < 2; ++i)
            fa[i] = *(const bf8_t*)&Ah[cur][(ta + i) * 512 + l * 8];
        #pragma unroll
        for (int j = 0; j < 4; ++j)
            fb[j] = *(const bf8_t*)&Bh[cur][(tb + j) * 512 + l * 8];
        #pragma unroll
        for (int i = 0; i < 2; ++i)
            #pragma unroll
            for (int j = 0; j < 4; ++j)
                acc[i][j] = __builtin_amdgcn_mfma_f32_16x16x32_bf16(fa[i], fb[j], acc[i][j], 0, 0, 0);
        // consume A prefetch: BN+ReLU -> bf16 -> LDS
        if (have)
            *(bf8_t*)&Ah[nxt][tid * 8] = bnpack(hv, s0, s1, t0, t1, nch, hid);
        __syncthreads();   // drains ds_write (lgkm) + B gloads (vmcnt)
        cur = nxt;
    }

    // epilogue: + sum-of-biases, leaky, store final (acc already sums the 3 link types)
    #pragma unroll
    for (int j = 0; j < 4; ++j) {
        int c = bn + wn + j * 16 + lane15;
        float bsum = bb[c] + bb[256 + c] + bb[512 + c];
        #pragma unroll
        for (int i = 0; i < 2; ++i) {
            #pragma unroll
            for (int r5 = 0; r5 < 4; ++r5) {
                int r = bm + wm + i * 16 + quad * 4 + r5;
                if (r < NN) {
                    float v = acc[i][j][r5] + bsum;
                    if (leaky) v = (v > 0.f) ? v : 0.01f * v;
                    if (as_bf16) outb[(size_t)r * 256 + c] = f2bf(v);
                    else         outf[(size_t)r * 256 + c] = v;
                }
            }
        }
    }
}

// ---------------- host ----------------

extern "C" void kernel_launch(void* const* d_in, const int* in_sizes, int n_in,
                              void* d_out, int out_size, void* d_ws, size_t ws_size,
                              hipStream_t stream)
{
    const float* x  = (const float*)d_in[0];
    const int*   ei = (const int*)d_in[1];
    const float* ea = (const float*)d_in[2];

    char* w = (char*)d_ws;
    auto alloc = [&](size_t bytes) {
        char* p = w;
        w += (bytes + 255) & ~(size_t)255;
        return p;
    };
    int* deg    = (int*)alloc((size_t)KT * NN * 4);
    int* offs   = (int*)alloc((size_t)KT * (NN + 1) * 4);
    int* cursor = (int*)alloc((size_t)KT * NN * 4);
    int2* se    = (int2*)alloc((size_t)KT * NE * 8);
    unsigned short* a1_hi = (unsigned short*)alloc((size_t)KT * NP * 256 * 2);
    unsigned short* h3 = (unsigned short*)alloc((size_t)KT * NP * 512 * 2);
    unsigned short* bta_l[3];
    unsigned short* btb_l[3];
    for (int l = 0; l < 3; ++l) {
        bta_l[l] = (unsigned short*)alloc((size_t)KT * 512 * 256 * 2);
        btb_l[l] = (unsigned short*)alloc((size_t)KT * 256 * 512 * 2);
    }
    float* psum = (float*)alloc((size_t)KT * (NP / 128) * 4 * 2 * 256 * 4);
    float* scale3 = (float*)alloc((size_t)KT * 512 * 4);
    float* shift3 = (float*)alloc((size_t)KT * 512 * 4);
    unsigned short* bufA = (unsigned short*)alloc((size_t)NN * 256 * 2);
    unsigned short* bufB = (unsigned short*)alloc((size_t)NN * 256 * 2);

    (void)hipMemsetAsync(deg, 0, (size_t)KT * NN * 4, stream);
    int net = KT * NE;
    deg_kernel<<<(net + 255) / 256, 256, 0, stream>>>(ei, deg);
    scan_kernel<<<KT, 256, 0, stream>>>(deg, offs, cursor);
    scatter_kernel<<<(net + 255) / 256, 256, 0, stream>>>(ei, ea, cursor, se);

    SplitJobs jobs;
    int maxtot = 0;
    for (int l = 0; l < 3; ++l) {
        int ci  = (l == 0) ? 170 : 256;
        int KP1 = (ci + 31) / 32 * 32;
        int hid = 2 * ci;
        int NHP = (hid + 127) / 128 * 128;
        int KP2 = (hid + 31) / 32 * 32;
        jobs.j[2 * l]     = { (const float*)d_in[3 + 8 * l + 2], bta_l[l], ci,  hid, NHP, KP1 };
        jobs.j[2 * l + 1] = { (const float*)d_in[3 + 8 * l + 6], btb_l[l], hid, 256, 256, KP2 };
        maxtot = max(maxtot, KT * NHP * KP1);
        maxtot = max(maxtot, KT * 256 * KP2);
    }
    dim3 gsp((maxtot + 255) / 256, 1, 6);
    split_all_kernel<<<gsp, 256, 0, stream>>>(jobs);

    const void* hin = x;
    for (int l = 0; l < 3; ++l) {
        int ci  = (l == 0) ? 170 : 256;
        int KP1 = (ci + 31) / 32 * 32;        // 192 / 256
        int hid = 2 * ci;                     // 340 / 512
        int NHP = (hid + 127) / 128 * 128;    // 384 / 512
        int KP2 = (hid + 31) / 32 * 32;       // 352 / 512
        const float* We = (const float*)d_in[3 + 8 * l + 0];
        const float* be = (const float*)d_in[3 + 8 * l + 1];
        const float* ba = (const float*)d_in[3 + 8 * l + 3];
        const float* g  = (const float*)d_in[3 + 8 * l + 4];
        const float* bt = (const float*)d_in[3 + 8 * l + 5];
        const float* bb = (const float*)d_in[3 + 8 * l + 7];

        dim3 ga(NP / 16, KT);
        if (l == 0)
            aggr_kernel<170, false><<<ga, 256, 0, stream>>>(hin, se, offs, We, be, a1_hi);
        else
            aggr_kernel<256, true><<<ga, 256, 0, stream>>>(hin, se, offs, We, be, a1_hi);

        dim3 g1(NHP / 128, NP / 128, KT);
        gemm1_mfma<<<g1, 256, 0, stream>>>(a1_hi, bta_l[l], ba, h3, psum, KP1, KP2, NN, hid);

        dim3 gf(KT, 8);
        finalize_kernel<<<gf, 256, 0, stream>>>(psum, g, bt, scale3, shift3, hid, NHP / 128);

        unsigned short* outb = (l == 0) ? bufA : bufB;
        dim3 g2(2, NP / 64);
        gemm2_mfma<<<g2, 256, 0, stream>>>(h3, scale3, shift3, btb_l[l], bb,
                                           (float*)d_out, outb, KP2, hid,
                                           (l < 2) ? 1 : 0, (l < 2) ? 1 : 0);

        hin = (l < 2) ? (const void*)outb : nullptr;
    }
}

// Round 11
// 648.982 us; speedup vs baseline: 1.7159x; 1.0060x over previous
//
#include <hip/hip_runtime.h>
#include <math.h>

#define NN 16500
#define NP 16512      // 129 * 128 padded rows
#define NE 100000
#define KT 3

typedef __attribute__((ext_vector_type(8))) short bf8_t;   // 8 x bf16
typedef __attribute__((ext_vector_type(4))) float f4_t;    // MFMA accumulator

__device__ __forceinline__ unsigned short f2bf(float f) {
    unsigned int u = __float_as_uint(f);
    u += 0x7fffu + ((u >> 16) & 1u);   // RNE
    return (unsigned short)(u >> 16);
}
__device__ __forceinline__ float bf2f(unsigned short h) {
    return __uint_as_float(((unsigned int)h) << 16);
}
__device__ __forceinline__ void gload16(unsigned short* lds, const unsigned short* g) {
    __builtin_amdgcn_global_load_lds(
        (const __attribute__((address_space(1))) void*)g,
        (__attribute__((address_space(3))) void*)lds, 16, 0, 0);
}

// ---------------- CSR build ----------------

__global__ void deg_kernel(const int* __restrict__ ei, int* __restrict__ deg) {
    int t = blockIdx.x * blockDim.x + threadIdx.x;
    if (t >= KT * NE) return;
    int k = t / NE, e = t - k * NE;
    int d = ei[k * 2 * NE + NE + e];
    atomicAdd(&deg[k * NN + d], 1);
}

__global__ void scan_kernel(const int* __restrict__ deg, int* __restrict__ offs,
                            int* __restrict__ cursor) {
    int k = blockIdx.x;
    const int* dg = deg + k * NN;
    int* of = offs + k * (NN + 1);
    int* cu = cursor + k * NN;
    __shared__ int part[256];
    int tid = threadIdx.x;
    const int chunk = (NN + 255) / 256;
    int s0 = tid * chunk, s1 = min(NN, s0 + chunk);
    if (s0 > s1) s0 = s1;
    int sum = 0;
    for (int i = s0; i < s1; ++i) sum += dg[i];
    part[tid] = sum;
    __syncthreads();
    for (int off = 1; off < 256; off <<= 1) {
        int v = part[tid];
        int vp = (tid >= off) ? part[tid - off] : 0;
        __syncthreads();
        part[tid] = v + vp;
        __syncthreads();
    }
    int run = (tid == 0) ? 0 : part[tid - 1];
    for (int i = s0; i < s1; ++i) {
        of[i] = run; cu[i] = run;
        run += dg[i];
    }
    if (tid == 255) of[NN] = run;
}

// scatter edge (src, ea) pairs directly in CSR order — removes one dependent
// gather level from the aggregation critical path.
__global__ void scatter_kernel(const int* __restrict__ ei, const float* __restrict__ ea,
                               int* __restrict__ cursor, int2* __restrict__ se) {
    int t = blockIdx.x * blockDim.x + threadIdx.x;
    if (t >= KT * NE) return;
    int k = t / NE, e = t - k * NE;
    int s = ei[k * 2 * NE + e];
    int d = ei[k * 2 * NE + NE + e];
    float a = ea[(size_t)k * NE + e];
    int pos = atomicAdd(&cursor[k * NN + d], 1);
    int2 p; p.x = s; p.y = __float_as_int(a);
    se[(size_t)k * NE + pos] = p;
}

// ---------------- softmax aggregation: one wave per (dst,k), 4 dsts/wave, depth-4 pipeline ----
// No-max online softmax: msg = relu(x_src + a*We + be) is bounded well below the
// fp32 exp overflow point for this BN-normalized pipeline, so we accumulate
// den = sum exp(msg), num = sum msg*exp(msg) directly.

template<int CI, bool BF16X>
__device__ __forceinline__ void loadrow4(float out[4], const void* xv, int s, int c0) {
    if (BF16X) {
        const unsigned short* xb = (const unsigned short*)xv;
        uint2 u = *(const uint2*)(xb + (size_t)s * CI + c0);
        out[0] = bf2f((unsigned short)(u.x & 0xffffu));
        out[1] = bf2f((unsigned short)(u.x >> 16));
        out[2] = bf2f((unsigned short)(u.y & 0xffffu));
        out[3] = bf2f((unsigned short)(u.y >> 16));
    } else {
        const float* p = (const float*)xv + (size_t)s * CI + c0;
        if (c0 + 4 <= CI) {
            float2 ab = *(const float2*)p;
            float2 cd = *(const float2*)(p + 2);
            out[0] = ab.x; out[1] = ab.y; out[2] = cd.x; out[3] = cd.y;
        } else {
            #pragma unroll
            for (int e = 0; e < 4; ++e) out[e] = (c0 + e < CI) ? p[e] : 0.f;
        }
    }
}

template<int CI, bool BF16X>
__global__ __launch_bounds__(256) void aggr_kernel(
    const void* __restrict__ xv, const int2* __restrict__ se_all,
    const int* __restrict__ offs_all,
    const float* __restrict__ We_all, const float* __restrict__ be_all,
    unsigned short* __restrict__ out_hi)
{
    constexpr int KP = (CI + 31) / 32 * 32;
    int k = blockIdx.y;
    int wv = threadIdx.x >> 6, lane = threadIdx.x & 63;
    int c0 = lane * 4;
    unsigned short* o = out_hi + (size_t)k * NP * KP;
    const int2*  se   = se_all + (size_t)k * NE;
    const int*   offs = offs_all + k * (NN + 1);
    const float* We   = We_all + (size_t)k * CI;
    const float* be   = be_all + (size_t)k * CI;

    constexpr bool ACT_ALL = (64 * 4 == KP) && (CI == KP);
    bool act = ACT_ALL || (c0 < CI);
    float w[4], b[4];
    #pragma unroll
    for (int e = 0; e < 4; ++e) {
        bool a = (c0 + e) < CI;
        w[e] = a ? We[c0 + e] : 0.f;
        b[e] = a ? be[c0 + e] : 0.f;
    }

    for (int it = 0; it < 4; ++it) {
        int d = blockIdx.x * 16 + it * 4 + wv;
        if (d >= NN) {
            if (c0 < KP) { uint2 z = {0u, 0u}; *(uint2*)(o + (size_t)d * KP + c0) = z; }
            continue;
        }
        float xd[4] = {0.f, 0.f, 0.f, 0.f};
        if (act) loadrow4<CI, BF16X>(xd, xv, d, c0);
        #pragma unroll
        for (int e = 0; e < 4; ++e) if ((c0 + e) >= CI) xd[e] = 0.f;

        float den[4], num[4];
        #pragma unroll
        for (int e = 0; e < 4; ++e) {
            float mg = fmaxf(xd[e] + w[e] + b[e], 0.f);   // self loop, ea=1
            float ex = __expf(mg);
            den[e] = ex;
            num[e] = mg * ex;
        }

        auto step = [&](const float xc[4], float a) {
            #pragma unroll
            for (int e = 0; e < 4; ++e) {
                float t = xc[e] + fmaf(a, w[e], b[e]);
                float mg = fmaxf(t, 0.f);
                float ex = __expf(mg);
                den[e] += ex;
                num[e] = fmaf(mg, ex, num[e]);
            }
        };

        int start = offs[d], end = offs[d + 1];
        for (int base = start; base < end; base += 64) {
            int cnt = min(64, end - base);
            int sv = 0; float av = 0.f;
            if (lane < cnt) {
                int2 p = se[base + lane];
                sv = p.x; av = __int_as_float(p.y);
            }
            float x0[4] = {0.f,0.f,0.f,0.f}, x1[4] = {0.f,0.f,0.f,0.f};
            float x2[4] = {0.f,0.f,0.f,0.f}, x3[4] = {0.f,0.f,0.f,0.f};
            {
                int sA = __shfl(sv, 0), sB = __shfl(sv, 1);
                int sC = __shfl(sv, 2), sD = __shfl(sv, 3);
                if (act)            loadrow4<CI, BF16X>(x0, xv, sA, c0);
                if (act && cnt > 1) loadrow4<CI, BF16X>(x1, xv, sB, c0);
                if (act && cnt > 2) loadrow4<CI, BF16X>(x2, xv, sC, c0);
                if (act && cnt > 3) loadrow4<CI, BF16X>(x3, xv, sD, c0);
            }
            int j = 0;
            for (; j + 3 < cnt; j += 4) {
                float a0 = __shfl(av, j),     a1 = __shfl(av, j + 1);
                float a2 = __shfl(av, j + 2), a3 = __shfl(av, j + 3);
                int s4 = __shfl(sv, (j + 4) & 63), s5 = __shfl(sv, (j + 5) & 63);
                int s6 = __shfl(sv, (j + 6) & 63), s7 = __shfl(sv, (j + 7) & 63);
                step(x0, a0);
                if (act && (j + 4) < cnt) loadrow4<CI, BF16X>(x0, xv, s4, c0);
                step(x1, a1);
                if (act && (j + 5) < cnt) loadrow4<CI, BF16X>(x1, xv, s5, c0);
                step(x2, a2);
                if (act && (j + 6) < cnt) loadrow4<CI, BF16X>(x2, xv, s6, c0);
                step(x3, a3);
                if (act && (j + 7) < cnt) loadrow4<CI, BF16X>(x3, xv, s7, c0);
            }
            if (j < cnt)     step(x0, __shfl(av, j));
            if (j + 1 < cnt) step(x1, __shfl(av, j + 1));
            if (j + 2 < cnt) step(x2, __shfl(av, j + 2));
        }
        if (c0 < KP) {
            unsigned short r[4];
            #pragma unroll
            for (int e = 0; e < 4; ++e) {
                float v = ((c0 + e) < CI) ? (num[e] / den[e] + xd[e]) : 0.f;
                r[e] = f2bf(v);
            }
            uint2 pk = {(unsigned)r[0] | ((unsigned)r[1] << 16),
                        (unsigned)r[2] | ((unsigned)r[3] << 16)};
            *(uint2*)(o + (size_t)d * KP + c0) = pk;
        }
    }
}

// ---------------- weight split+transpose, all 6 jobs in one launch ----------------

struct SplitJob { const float* W; unsigned short* out; int kdim, ndim, np_, kp; };
struct SplitJobs { SplitJob j[6]; };

__global__ void split_all_kernel(SplitJobs jobs) {
    SplitJob jb = jobs.j[blockIdx.z];
    int idx = blockIdx.x * 256 + threadIdx.x;
    int total = KT * jb.np_ * jb.kp;
    if (idx >= total) return;
    int k = idx / (jb.np_ * jb.kp);
    int rem = idx - k * jb.np_ * jb.kp;
    int n = rem / jb.kp;
    int kk = rem - n * jb.kp;
    float v = (n < jb.ndim && kk < jb.kdim) ? jb.W[((size_t)k * jb.kdim + kk) * jb.ndim + n] : 0.f;
    jb.out[idx] = f2bf(v);
}

// ---------------- GEMM1: bf16 MFMA, dbuf K-loop, fused BN stats, LDS-coalesced C store ------
// (round-9 win: LDS C-bounce removes ~4.8x HBM write amplification)

__global__ __launch_bounds__(256, 2) void gemm1_mfma(
    const unsigned short* __restrict__ A_hi,
    const unsigned short* __restrict__ B_hi,
    const float* __restrict__ bias_all, unsigned short* __restrict__ C_all,
    float* __restrict__ psum,
    int KP, int ldc, int Mv, int Nv)
{
    __shared__ unsigned short smem[16384];   // A dbuf [0|4096], B dbuf [8192|12288]; reused as Ct[128][128]

    int z = blockIdx.z;
    int gxT = gridDim.x, gyT = gridDim.y;
    int NHP = gxT * 128;
    const unsigned short* Ahg = A_hi + (size_t)z * NP * KP;
    const unsigned short* Bhg = B_hi + (size_t)z * NHP * KP;
    const float* bias = bias_all + (size_t)z * Nv;
    unsigned short* C = C_all + (size_t)z * NP * ldc;

    int tid = threadIdx.x;
    int w = tid >> 6, l = tid & 63;
    int bm = blockIdx.y * 128, bn = blockIdx.x * 128;
    int lane15 = l & 15, quad = l >> 4;
    int wm = (w >> 1) * 64, wn = (w & 1) * 64;
    int srow = l & 15;
    int scol = (l >> 4) * 8;

    f4_t acc[4][4];
    #pragma unroll
    for (int i = 0; i < 4; ++i)
        #pragma unroll
        for (int j = 0; j < 4; ++j) { f4_t zz = {0.f,0.f,0.f,0.f}; acc[i][j] = zz; }

    size_t aoff0 = (size_t)(bm + 32 * w +  0 + srow) * KP + scol;
    size_t aoff1 = (size_t)(bm + 32 * w + 16 + srow) * KP + scol;
    size_t boff0 = (size_t)(bn + 32 * w +  0 + srow) * KP + scol;
    size_t boff1 = (size_t)(bn + 32 * w + 16 + srow) * KP + scol;
    int rb0 = 32 * w, rb1 = 32 * w + 16;
    int ta = (w >> 1) * 4, tb = (w & 1) * 4;

    // prologue: stage tile 0 into offset 0
    gload16(&smem[0 + rb0 * 32], Ahg + aoff0);
    gload16(&smem[0 + rb1 * 32], Ahg + aoff1);
    gload16(&smem[8192 + rb0 * 32], Bhg + boff0);
    gload16(&smem[8192 + rb1 * 32], Bhg + boff1);
    __syncthreads();

    int curo = 0;
    for (int k0 = 32; k0 < KP; k0 += 32) {
        int nxto = curo ^ 4096;
        gload16(&smem[nxto + rb0 * 32], Ahg + aoff0 + k0);
        gload16(&smem[nxto + rb1 * 32], Ahg + aoff1 + k0);
        gload16(&smem[8192 + nxto + rb0 * 32], Bhg + boff0 + k0);
        gload16(&smem[8192 + nxto + rb1 * 32], Bhg + boff1 + k0);

        bf8_t fa[4], fb[4];
        #pragma unroll
        for (int i = 0; i < 4; ++i) {
            fa[i] = *(const bf8_t*)&smem[curo + (ta + i) * 512 + l * 8];
            fb[i] = *(const bf8_t*)&smem[8192 + curo + (tb + i) * 512 + l * 8];
        }
        #pragma unroll
        for (int i = 0; i < 4; ++i)
            #pragma unroll
            for (int j = 0; j < 4; ++j)
                acc[i][j] = __builtin_amdgcn_mfma_f32_16x16x32_bf16(fa[i], fb[j], acc[i][j], 0, 0, 0);
        __syncthreads();
        curo = nxto;
    }
    {   // last tile
        bf8_t fa[4], fb[4];
        #pragma unroll
        for (int i = 0; i < 4; ++i) {
            fa[i] = *(const bf8_t*)&smem[curo + (ta + i) * 512 + l * 8];
            fb[i] = *(const bf8_t*)&smem[8192 + curo + (tb + i) * 512 + l * 8];
        }
        #pragma unroll
        for (int i = 0; i < 4; ++i)
            #pragma unroll
            for (int j = 0; j < 4; ++j)
                acc[i][j] = __builtin_amdgcn_mfma_f32_16x16x32_bf16(fa[i], fb[j], acc[i][j], 0, 0, 0);
    }

    __syncthreads();   // all waves done reading staging buffers; safe to reuse as C tile

    // quantize + fused BN partial stats (identical arithmetic to before); C -> LDS
    #pragma unroll
    for (int j = 0; j < 4; ++j) {
        int c = bn + wn + j * 16 + lane15;
        float bc = (c < Nv) ? bias[c] : 0.f;
        float s1 = 0.f, s2 = 0.f;
        #pragma unroll
        for (int i = 0; i < 4; ++i) {
            #pragma unroll
            for (int r5 = 0; r5 < 4; ++r5) {
                int r = bm + wm + i * 16 + quad * 4 + r5;
                float v = acc[i][j][r5] + bc;
                unsigned short q = f2bf(v);
                int lr = wm + i * 16 + quad * 4 + r5;
                int lc = wn + j * 16 + lane15;
                smem[lr * 128 + lc] = q;
                bool ok = (r < NN) && (c < Nv);
                float vq = ok ? bf2f(q) : 0.f;
                s1 += vq;
                s2 = fmaf(vq, vq, s2);
            }
        }
        s1 += __shfl_xor(s1, 16); s2 += __shfl_xor(s2, 16);
        s1 += __shfl_xor(s1, 32); s2 += __shfl_xor(s2, 32);
        if (quad == 0) {
            int wrow = w >> 1;
            int col = wn + j * 16 + lane15;
            size_t o = ((((size_t)z * gyT + blockIdx.y) * gxT + blockIdx.x) * 2 + wrow) * 256 + col * 2;
            float2 st = {s1, s2};
            *(float2*)&psum[o] = st;
        }
    }
    __syncthreads();

    // coalesced C store: 16 lanes x 16B = 256B contiguous per row segment
    int lr8 = tid >> 4;              // row 0..15 base
    int lc8 = (tid & 15) * 8;        // col 0..120
    bool cok = (bn + lc8 + 8) <= ldc;   // l=0 last tile: cols >= ldc don't exist
    if (cok) {
        #pragma unroll
        for (int p = 0; p < 8; ++p) {
            int row = p * 16 + lr8;
            uint4 v = *(const uint4*)&smem[row * 128 + lc8];
            *(uint4*)&C[(size_t)(bm + row) * ldc + bn + lc8] = v;
        }
    }
}

// ---------------- finalize BN scale/shift from partials (parallel over channel chunks) ---------

__global__ __launch_bounds__(256) void finalize_kernel(
    const float* __restrict__ psum,
    const float* __restrict__ g_all, const float* __restrict__ bt_all,
    float* __restrict__ scale_all, float* __restrict__ shift_all,
    int hid, int gxT)
{
    int z = blockIdx.x;
    int t64 = threadIdx.x & 63;
    int slice = threadIdx.x >> 6;          // 0..3 gy-slices
    int c = blockIdx.y * 64 + t64;         // channel
    __shared__ double rs1[4][64];
    __shared__ double rs2[4][64];
    double s1 = 0.0, s2 = 0.0;
    if (c < gxT * 128) {
        int gx = c >> 7, col = c & 127;
        for (int gy = slice; gy < NP / 128; gy += 4) {
            size_t base = (((size_t)z * (NP / 128) + gy) * gxT + gx) * 2 * 256 + col * 2;
            float2 a  = *(const float2*)&psum[base];
            float2 b2 = *(const float2*)&psum[base + 256];
            s1 += (double)a.x + b2.x;
            s2 += (double)a.y + b2.y;
        }
    }
    rs1[slice][t64] = s1;
    rs2[slice][t64] = s2;
    __syncthreads();
    if (slice == 0 && c < hid) {
        double S1 = rs1[0][t64] + rs1[1][t64] + rs1[2][t64] + rs1[3][t64];
        double S2 = rs2[0][t64] + rs2[1][t64] + rs2[2][t64] + rs2[3][t64];
        double mu = S1 / NN;
        double var = S2 / NN - mu * mu;
        if (var < 0.0) var = 0.0;
        float rs = (float)(1.0 / sqrt(var + 1e-5));
        float sc = rs * g_all[(size_t)z * hid + c];
        scale_all[(size_t)z * 512 + c] = sc;
        shift_all[(size_t)z * 512 + c] = bt_all[(size_t)z * hid + c] - (float)mu * sc;
    }
}

// ---------------- GEMM2: z-fused 64x128 tile, ALL operands via global_load_lds --------------
// Round-10 change: A (h) is staged RAW via gload_lds (dst Ah[buf][tid*8] is exactly
// wave-uniform-base + lane*16; per-lane src = h[bm+16w+(l&15)][kk + (l>>4)*8]). The
// BN+ReLU transform moves to AFTER the fragment ds_read — same channels per lane, so
// arithmetic is bit-identical to the old pre-LDS bnpack. scale/shift live in an LDS
// copy, so the K-loop contains no VMEM except the 3 prefetch DMAs: this deletes the
// serial hv-load wait + ds_write + lgkm-drain from every iteration.

__global__ __launch_bounds__(256, 2) void gemm2_mfma(
    const unsigned short* __restrict__ h_all, const float* __restrict__ scale_all,
    const float* __restrict__ shift_all,
    const unsigned short* __restrict__ B_hi,
    const float* __restrict__ bb,
    float* __restrict__ outf, unsigned short* __restrict__ outb,
    int KP, int hid, int leaky, int as_bf16)
{
    __shared__ unsigned short Ah[2][64 * 32];    // 8 KB
    __shared__ unsigned short Bh[2][128 * 32];   // 16 KB
    __shared__ float sclS[KT * 512];             // 6 KB
    __shared__ float shfS[KT * 512];             // 6 KB

    int tid = threadIdx.x;
    int w = tid >> 6, l = tid & 63;
    int bm = blockIdx.y * 64, bn = blockIdx.x * 128;
    int lane15 = l & 15, quad = l >> 4;
    int wm = (w >> 1) * 32, wn = (w & 1) * 64;
    int srow = l & 15, scol = (l >> 4) * 8;

    const int KPZ = KP / 32;
    const int NIT = 3 * KPZ;

    f4_t acc[2][4];
    #pragma unroll
    for (int i = 0; i < 2; ++i)
        #pragma unroll
        for (int j = 0; j < 4; ++j) { f4_t zz = {0.f,0.f,0.f,0.f}; acc[i][j] = zz; }

    int rb0 = 32 * w, rb1 = 32 * w + 16;
    int ta = (w >> 1) * 2, tb = (w & 1) * 4;
    int grow = 16 * w + lane15;                  // A row this thread stages
    int ccol = quad * 8;                         // A col offset within k-slab

    size_t arow  = (size_t)(bm + grow) * KP + ccol;
    size_t brow0 = (size_t)(bn + 32 * w + srow) * KP + scol;
    size_t brow1 = (size_t)(bn + 32 * w + 16 + srow) * KP + scol;

    // prologue: scale/shift -> LDS; stage tile 0
    for (int idx = tid; idx < KT * 512; idx += 256) {
        sclS[idx] = scale_all[idx];
        shfS[idx] = shift_all[idx];
    }
    gload16(&Ah[0][tid * 8], h_all + arow);
    gload16(&Bh[0][rb0 * 32], B_hi + brow0);
    gload16(&Bh[0][rb1 * 32], B_hi + brow1);
    __syncthreads();

    int cur = 0;
    for (int it = 0; it < NIT; ++it) {
        int nit = it + 1;
        int nxt = cur ^ 1;
        if (nit < NIT) {
            int nzz = nit / KPZ, nkk = (nit - nzz * KPZ) * 32;
            const unsigned short* hz = h_all + (size_t)nzz * NP * KP + nkk;
            const unsigned short* bz = B_hi + (size_t)nzz * 256 * KP + nkk;
            gload16(&Ah[nxt][tid * 8], hz + arow);
            gload16(&Bh[nxt][rb0 * 32], bz + brow0);
            gload16(&Bh[nxt][rb1 * 32], bz + brow1);
        }
        int zz = it / KPZ, kk = (it - zz * KPZ) * 32;
        int chb = kk + quad * 8;
        // BN params from LDS (broadcast within quad groups, conflict-free)
        float4 s0 = *(const float4*)&sclS[zz * 512 + chb];
        float4 s1 = *(const float4*)&sclS[zz * 512 + chb + 4];
        float4 t0 = *(const float4*)&shfS[zz * 512 + chb];
        float4 t1 = *(const float4*)&shfS[zz * 512 + chb + 4];
        float ss[8] = {s0.x, s0.y, s0.z, s0.w, s1.x, s1.y, s1.z, s1.w};
        float tt[8] = {t0.x, t0.y, t0.z, t0.w, t1.x, t1.y, t1.z, t1.w};
        // fragments
        bf8_t fr0 = *(const bf8_t*)&Ah[cur][(ta + 0) * 512 + l * 8];
        bf8_t fr1 = *(const bf8_t*)&Ah[cur][(ta + 1) * 512 + l * 8];
        bf8_t fb[4];
        #pragma unroll
        for (int j = 0; j < 4; ++j)
            fb[j] = *(const bf8_t*)&Bh[cur][(tb + j) * 512 + l * 8];
        // BN+ReLU in registers (same channels per lane as pre-LDS bnpack: ch = chb+e)
        bf8_t fa0, fa1;
        #pragma unroll
        for (int e = 0; e < 8; ++e) {
            bool okc = (chb + e) < hid;
            float x0 = bf2f((unsigned short)fr0[e]);
            float x1 = bf2f((unsigned short)fr1[e]);
            float v0 = okc ? fmaxf(fmaf(x0, ss[e], tt[e]), 0.f) : 0.f;
            float v1 = okc ? fmaxf(fmaf(x1, ss[e], tt[e]), 0.f) : 0.f;
            fa0[e] = (short)f2bf(v0);
            fa1[e] = (short)f2bf(v1);
        }
        #pragma unroll
        for (int j = 0; j < 4; ++j) {
            acc[0][j] = __builtin_amdgcn_mfma_f32_16x16x32_bf16(fa0, fb[j], acc[0][j], 0, 0, 0);
            acc[1][j] = __builtin_amdgcn_mfma_f32_16x16x32_bf16(fa1, fb[j], acc[1][j], 0, 0, 0);
        }
        __syncthreads();   // drains the 3 prefetch DMAs (vmcnt) + publishes next buffer
        cur = nxt;
    }

    // epilogue: + sum-of-biases, leaky, store final (acc already sums the 3 link types)
    #pragma unroll
    for (int j = 0; j < 4; ++j) {
        int c = bn + wn + j * 16 + lane15;
        float bsum = bb[c] + bb[256 + c] + bb[512 + c];
        #pragma unroll
        for (int i = 0; i < 2; ++i) {
            #pragma unroll
            for (int r5 = 0; r5 < 4; ++r5) {
                int r = bm + wm + i * 16 + quad * 4 + r5;
                if (r < NN) {
                    float v = acc[i][j][r5] + bsum;
                    if (leaky) v = (v > 0.f) ? v : 0.01f * v;
                    if (as_bf16) outb[(size_t)r * 256 + c] = f2bf(v);
                    else         outf[(size_t)r * 256 + c] = v;
                }
            }
        }
    }
}

// ---------------- host ----------------

extern "C" void kernel_launch(void* const* d_in, const int* in_sizes, int n_in,
                              void* d_out, int out_size, void* d_ws, size_t ws_size,
                              hipStream_t stream)
{
    const float* x  = (const float*)d_in[0];
    const int*   ei = (const int*)d_in[1];
    const float* ea = (const float*)d_in[2];

    char* w = (char*)d_ws;
    auto alloc = [&](size_t bytes) {
        char* p = w;
        w += (bytes + 255) & ~(size_t)255;
        return p;
    };
    int* deg    = (int*)alloc((size_t)KT * NN * 4);
    int* offs   = (int*)alloc((size_t)KT * (NN + 1) * 4);
    int* cursor = (int*)alloc((size_t)KT * NN * 4);
    int2* se    = (int2*)alloc((size_t)KT * NE * 8);
    unsigned short* a1_hi = (unsigned short*)alloc((size_t)KT * NP * 256 * 2);
    unsigned short* h3 = (unsigned short*)alloc((size_t)KT * NP * 512 * 2);
    unsigned short* bta_l[3];
    unsigned short* btb_l[3];
    for (int l = 0; l < 3; ++l) {
        bta_l[l] = (unsigned short*)alloc((size_t)KT * 512 * 256 * 2);
        btb_l[l] = (unsigned short*)alloc((size_t)KT * 256 * 512 * 2);
    }
    float* psum = (float*)alloc((size_t)KT * (NP / 128) * 4 * 2 * 256 * 4);
    float* scale3 = (float*)alloc((size_t)KT * 512 * 4);
    float* shift3 = (float*)alloc((size_t)KT * 512 * 4);
    unsigned short* bufA = (unsigned short*)alloc((size_t)NN * 256 * 2);
    unsigned short* bufB = (unsigned short*)alloc((size_t)NN * 256 * 2);

    (void)hipMemsetAsync(deg, 0, (size_t)KT * NN * 4, stream);
    int net = KT * NE;
    deg_kernel<<<(net + 255) / 256, 256, 0, stream>>>(ei, deg);
    scan_kernel<<<KT, 256, 0, stream>>>(deg, offs, cursor);
    scatter_kernel<<<(net + 255) / 256, 256, 0, stream>>>(ei, ea, cursor, se);

    SplitJobs jobs;
    int maxtot = 0;
    for (int l = 0; l < 3; ++l) {
        int ci  = (l == 0) ? 170 : 256;
        int KP1 = (ci + 31) / 32 * 32;
        int hid = 2 * ci;
        int NHP = (hid + 127) / 128 * 128;
        int KP2 = (hid + 31) / 32 * 32;
        jobs.j[2 * l]     = { (const float*)d_in[3 + 8 * l + 2], bta_l[l], ci,  hid, NHP, KP1 };
        jobs.j[2 * l + 1] = { (const float*)d_in[3 + 8 * l + 6], btb_l[l], hid, 256, 256, KP2 };
        maxtot = max(maxtot, KT * NHP * KP1);
        maxtot = max(maxtot, KT * 256 * KP2);
    }
    dim3 gsp((maxtot + 255) / 256, 1, 6);
    split_all_kernel<<<gsp, 256, 0, stream>>>(jobs);

    const void* hin = x;
    for (int l = 0; l < 3; ++l) {
        int ci  = (l == 0) ? 170 : 256;
        int KP1 = (ci + 31) / 32 * 32;        // 192 / 256
        int hid = 2 * ci;                     // 340 / 512
        int NHP = (hid + 127) / 128 * 128;    // 384 / 512
        int KP2 = (hid + 31) / 32 * 32;       // 352 / 512
        const float* We = (const float*)d_in[3 + 8 * l + 0];
        const float* be = (const float*)d_in[3 + 8 * l + 1];
        const float* ba = (const float*)d_in[3 + 8 * l + 3];
        const float* g  = (const float*)d_in[3 + 8 * l + 4];
        const float* bt = (const float*)d_in[3 + 8 * l + 5];
        const float* bb = (const float*)d_in[3 + 8 * l + 7];

        dim3 ga(NP / 16, KT);
        if (l == 0)
            aggr_kernel<170, false><<<ga, 256, 0, stream>>>(hin, se, offs, We, be, a1_hi);
        else
            aggr_kernel<256, true><<<ga, 256, 0, stream>>>(hin, se, offs, We, be, a1_hi);

        dim3 g1(NHP / 128, NP / 128, KT);
        gemm1_mfma<<<g1, 256, 0, stream>>>(a1_hi, bta_l[l], ba, h3, psum, KP1, KP2, NN, hid);

        dim3 gf(KT, 8);
        finalize_kernel<<<gf, 256, 0, stream>>>(psum, g, bt, scale3, shift3, hid, NHP / 128);

        unsigned short* outb = (l == 0) ? bufA : bufB;
        dim3 g2(2, NP / 64);
        gemm2_mfma<<<g2, 256, 0, stream>>>(h3, scale3, shift3, btb_l[l], bb,
                                           (float*)d_out, outb, KP2, hid,
                                           (l < 2) ? 1 : 0, (l < 2) ? 1 : 0);

        hin = (l < 2) ? (const void*)outb : nullptr;
    }
}